// Round 1
// baseline (665.925 us; speedup 1.0000x reference)
//
#include <hip/hip_runtime.h>
#include <cstddef>

#define BB   8
#define TT   1024
#define DDIM 128
#define HH   8
#define DHH  16
#define FF   256
#define BT   (BB * TT)   // 8192

// ---------------------------------------------------------------------------
// LayerNorm: one 64-thread wave per row of 128. blockIdx.y selects x/y tensor.
// ---------------------------------------------------------------------------
__global__ __launch_bounds__(64) void ln_k(const float* __restrict__ X,
                                           const float* __restrict__ Y,
                                           const float* __restrict__ gx,
                                           const float* __restrict__ bx,
                                           const float* __restrict__ gy,
                                           const float* __restrict__ by,
                                           float* __restrict__ ox,
                                           float* __restrict__ oy) {
  const int row = blockIdx.x;
  const int which = blockIdx.y;
  const float* in = which ? Y : X;
  const float* g  = which ? gy : gx;
  const float* b  = which ? by : bx;
  float* out      = which ? oy : ox;
  const int tid = threadIdx.x;

  float2 v = *(const float2*)(in + (size_t)row * DDIM + tid * 2);
  float s  = v.x + v.y;
  float sq = v.x * v.x + v.y * v.y;
  #pragma unroll
  for (int off = 32; off >= 1; off >>= 1) {
    s  += __shfl_xor(s, off);
    sq += __shfl_xor(sq, off);
  }
  const float mean = s * (1.0f / DDIM);
  const float var  = sq * (1.0f / DDIM) - mean * mean;
  const float r    = rsqrtf(var + 1e-5f);

  float2 gg = *(const float2*)(g + tid * 2);
  float2 bb = *(const float2*)(b + tid * 2);
  float2 o;
  o.x = (v.x - mean) * r * gg.x + bb.x;
  o.y = (v.y - mean) * r * gg.y + bb.y;
  *(float2*)(out + (size_t)row * DDIM + tid * 2) = o;
}

// ---------------------------------------------------------------------------
// Generic batched GEMM: C = A(M,K) @ W(K,N) [+bias] [gelu] [+res]
// 64x64 tile / block, 256 threads, 4x4 micro-tile, BK=32.
// ---------------------------------------------------------------------------
struct GemmP { const float* A; const float* W; const float* bias; const float* res; float* C; };
struct GemmArgs { GemmP p[6]; int K; int N; int gelu; };

__global__ __launch_bounds__(256) void gemm_k(GemmArgs a) {
  const GemmP pp = a.p[blockIdx.z];
  const int K = a.K, N = a.N;
  const int n0 = blockIdx.x * 64, m0 = blockIdx.y * 64;
  __shared__ float As[32][68];   // As[k][m] (transposed), padded
  __shared__ float Bs[32][68];   // Bs[k][n], padded
  const int tid = threadIdx.x;
  const int ty = tid >> 4, tx = tid & 15;
  float acc[4][4] = {};

  for (int k0 = 0; k0 < K; k0 += 32) {
    #pragma unroll
    for (int t = tid; t < 512; t += 256) {
      const int row = t >> 3, c4 = (t & 7) << 2;
      float4 v = *(const float4*)(pp.A + (size_t)(m0 + row) * K + k0 + c4);
      As[c4 + 0][row] = v.x; As[c4 + 1][row] = v.y;
      As[c4 + 2][row] = v.z; As[c4 + 3][row] = v.w;
    }
    #pragma unroll
    for (int t = tid; t < 512; t += 256) {
      const int row = t >> 4, c4 = (t & 15) << 2;
      *(float4*)&Bs[row][c4] = *(const float4*)(pp.W + (size_t)(k0 + row) * N + n0 + c4);
    }
    __syncthreads();
    #pragma unroll
    for (int k = 0; k < 32; ++k) {
      const float4 a4 = *(const float4*)&As[k][ty << 2];
      const float4 b4 = *(const float4*)&Bs[k][tx << 2];
      const float av[4] = {a4.x, a4.y, a4.z, a4.w};
      const float bv[4] = {b4.x, b4.y, b4.z, b4.w};
      #pragma unroll
      for (int i = 0; i < 4; ++i)
        #pragma unroll
        for (int j = 0; j < 4; ++j)
          acc[i][j] = fmaf(av[i], bv[j], acc[i][j]);
    }
    __syncthreads();
  }

  #pragma unroll
  for (int i = 0; i < 4; ++i) {
    const int m = m0 + (ty << 2) + i;
    #pragma unroll
    for (int j = 0; j < 4; ++j) {
      const int n = n0 + (tx << 2) + j;
      float v = acc[i][j];
      if (pp.bias) v += pp.bias[n];
      if (a.gelu) v = 0.5f * v * (1.0f + erff(v * 0.70710678118654752f));
      if (pp.res) v += pp.res[(size_t)m * N + n];
      pp.C[(size_t)m * N + n] = v;
    }
  }
}

// ---------------------------------------------------------------------------
// Fused cross-attention, both branches share one softmax:
//   S = (qx.kx + qy.ky) * 0.125  ==  [qx|qy] . [kx|ky]  (d=32) * 0.125
//   O = softmax(S) @ [vx|vy]  -> split cols into o1 (0..15), o2 (16..31)
// Flash-style: 64 query rows / block, 16 key tiles of 64, online softmax.
// grid = (T/64, B*H), 256 threads (ty 0..15 -> 4 rows, tx 0..15).
// ---------------------------------------------------------------------------
__global__ __launch_bounds__(256) void attn_k(const float* __restrict__ qx,
                                              const float* __restrict__ kx,
                                              const float* __restrict__ vx,
                                              const float* __restrict__ qy,
                                              const float* __restrict__ ky,
                                              const float* __restrict__ vy,
                                              float* __restrict__ o1,
                                              float* __restrict__ o2) {
  const int t0 = blockIdx.x * 64;
  const int bh = blockIdx.y;
  const int b = bh >> 3, h = bh & 7;
  const size_t base = (size_t)b * TT * DDIM + h * DHH;

  __shared__ float Qs[64][36];  // [row][d0..31]
  __shared__ float Kt[32][68];  // [d][j]  (transposed)
  __shared__ float Vs[64][36];  // [j][c0..31]
  __shared__ float Ps[64][68];  // [row][j]

  const int tid = threadIdx.x;
  const int ty = tid >> 4, tx = tid & 15;

  // load Q tile (64 rows x 32) once
  #pragma unroll
  for (int t = tid; t < 512; t += 256) {
    const int row = t >> 3, c4 = t & 7;
    const float* src = (c4 < 4) ? qx : qy;
    const int d = (c4 & 3) << 2;
    float4 v = *(const float4*)(src + base + (size_t)(t0 + row) * DDIM + d);
    *(float4*)&Qs[row][(c4 < 4 ? 0 : 16) + d] = v;
  }

  float m_i[4], l_i[4], accO[4][2];
  #pragma unroll
  for (int i = 0; i < 4; ++i) {
    m_i[i] = -1e30f; l_i[i] = 0.f; accO[i][0] = 0.f; accO[i][1] = 0.f;
  }

  for (int kt = 0; kt < TT / 64; ++kt) {
    const int s0 = kt * 64;
    // load K tile (transposed) and V tile
    #pragma unroll
    for (int t = tid; t < 512; t += 256) {
      const int row = t >> 3, c4 = t & 7;
      const int dd = (c4 < 4 ? 0 : 16) + ((c4 & 3) << 2);
      {
        const float* src = (c4 < 4) ? kx : ky;
        float4 v = *(const float4*)(src + base + (size_t)(s0 + row) * DDIM + ((c4 & 3) << 2));
        Kt[dd + 0][row] = v.x; Kt[dd + 1][row] = v.y;
        Kt[dd + 2][row] = v.z; Kt[dd + 3][row] = v.w;
      }
      {
        const float* src = (c4 < 4) ? vx : vy;
        float4 v = *(const float4*)(src + base + (size_t)(s0 + row) * DDIM + ((c4 & 3) << 2));
        *(float4*)&Vs[row][dd] = v;
      }
    }
    __syncthreads();

    // S = Q' . K'^T  (4x4 per thread), cols j = tx*4+jl, rows r = ty*4+i
    float s[4][4] = {};
    #pragma unroll
    for (int d4 = 0; d4 < 8; ++d4) {
      float4 q[4], kk[4];
      #pragma unroll
      for (int i = 0; i < 4; ++i) q[i] = *(const float4*)&Qs[(ty << 2) + i][d4 << 2];
      #pragma unroll
      for (int d = 0; d < 4; ++d) kk[d] = *(const float4*)&Kt[(d4 << 2) + d][tx << 2];
      #pragma unroll
      for (int i = 0; i < 4; ++i) {
        const float qv[4] = {q[i].x, q[i].y, q[i].z, q[i].w};
        #pragma unroll
        for (int d = 0; d < 4; ++d) {
          s[i][0] = fmaf(qv[d], kk[d].x, s[i][0]);
          s[i][1] = fmaf(qv[d], kk[d].y, s[i][1]);
          s[i][2] = fmaf(qv[d], kk[d].z, s[i][2]);
          s[i][3] = fmaf(qv[d], kk[d].w, s[i][3]);
        }
      }
    }

    // online softmax update (row groups = 16 lanes sharing ty)
    #pragma unroll
    for (int i = 0; i < 4; ++i) {
      float s0v = s[i][0] * 0.125f, s1v = s[i][1] * 0.125f;
      float s2v = s[i][2] * 0.125f, s3v = s[i][3] * 0.125f;
      float mx = fmaxf(fmaxf(s0v, s1v), fmaxf(s2v, s3v));
      #pragma unroll
      for (int off = 8; off >= 1; off >>= 1) mx = fmaxf(mx, __shfl_xor(mx, off, 16));
      const float mn = fmaxf(m_i[i], mx);
      const float alpha = __expf(m_i[i] - mn);
      m_i[i] = mn;
      const float p0 = __expf(s0v - mn), p1 = __expf(s1v - mn);
      const float p2 = __expf(s2v - mn), p3 = __expf(s3v - mn);
      float rs = p0 + p1 + p2 + p3;
      #pragma unroll
      for (int off = 8; off >= 1; off >>= 1) rs += __shfl_xor(rs, off, 16);
      l_i[i] = l_i[i] * alpha + rs;
      accO[i][0] *= alpha; accO[i][1] *= alpha;
      *(float4*)&Ps[(ty << 2) + i][tx << 2] = make_float4(p0, p1, p2, p3);
    }
    __syncthreads();

    // O += P @ V'  (cols c = tx*2 + {0,1})
    #pragma unroll
    for (int j4 = 0; j4 < 16; ++j4) {
      float4 p[4];
      float2 v[4];
      #pragma unroll
      for (int i = 0; i < 4; ++i) p[i] = *(const float4*)&Ps[(ty << 2) + i][j4 << 2];
      #pragma unroll
      for (int jj = 0; jj < 4; ++jj) v[jj] = *(const float2*)&Vs[(j4 << 2) + jj][tx << 1];
      #pragma unroll
      for (int i = 0; i < 4; ++i) {
        const float pv[4] = {p[i].x, p[i].y, p[i].z, p[i].w};
        #pragma unroll
        for (int jj = 0; jj < 4; ++jj) {
          accO[i][0] = fmaf(pv[jj], v[jj].x, accO[i][0]);
          accO[i][1] = fmaf(pv[jj], v[jj].y, accO[i][1]);
        }
      }
    }
    __syncthreads();
  }

  // epilogue: normalize, split to o1/o2
  #pragma unroll
  for (int i = 0; i < 4; ++i) {
    const float inv = 1.0f / l_i[i];
    const int r = t0 + (ty << 2) + i;
    float2 o;
    o.x = accO[i][0] * inv; o.y = accO[i][1] * inv;
    if (tx < 8)
      *(float2*)(o1 + base + (size_t)r * DDIM + (tx << 1)) = o;
    else
      *(float2*)(o2 + base + (size_t)r * DDIM + ((tx << 1) - 16)) = o;
  }
}

// ---------------------------------------------------------------------------
extern "C" void kernel_launch(void* const* d_in, const int* in_sizes, int n_in,
                              void* d_out, int out_size, void* d_ws, size_t ws_size,
                              hipStream_t stream) {
  const float* x_in  = (const float*)d_in[0];
  const float* y_in  = (const float*)d_in[1];
  const float* Wq    = (const float*)d_in[2];
  const float* Wk    = (const float*)d_in[3];
  const float* Wv    = (const float*)d_in[4];
  const float* Wox   = (const float*)d_in[5];
  const float* box   = (const float*)d_in[6];
  const float* Woy   = (const float*)d_in[7];
  const float* boy   = (const float*)d_in[8];
  const float* ln1xg = (const float*)d_in[9];
  const float* ln1xb = (const float*)d_in[10];
  const float* ln1yg = (const float*)d_in[11];
  const float* ln1yb = (const float*)d_in[12];
  const float* ln2xg = (const float*)d_in[13];
  const float* ln2xb = (const float*)d_in[14];
  const float* ln2yg = (const float*)d_in[15];
  const float* ln2yb = (const float*)d_in[16];
  const float* fxw1  = (const float*)d_in[17];
  const float* fxb1  = (const float*)d_in[18];
  const float* fxw2  = (const float*)d_in[19];
  const float* fxb2  = (const float*)d_in[20];
  const float* fyw1  = (const float*)d_in[21];
  const float* fyb1  = (const float*)d_in[22];
  const float* fyw2  = (const float*)d_in[23];
  const float* fyb2  = (const float*)d_in[24];

  const size_t S = (size_t)BT * DDIM;  // 1M floats
  float* X = (float*)d_out;
  float* Y = X + S;
  float* w  = (float*)d_ws;
  float* xn = w + 0 * S;
  float* yn = w + 1 * S;
  float* qx = w + 2 * S;
  float* kx = w + 3 * S;
  float* vx = w + 4 * S;
  float* qy = w + 5 * S;
  float* ky = w + 6 * S;
  float* vy = w + 7 * S;
  float* ob1 = w + 8 * S;
  float* ob2 = w + 9 * S;
  float* hx = w + 2 * S;   // reuse qx/kx after attention (2S floats)
  float* hy = w + 4 * S;   // reuse vx/qy after attention

  hipMemcpyAsync(X, x_in, S * sizeof(float), hipMemcpyDeviceToDevice, stream);
  hipMemcpyAsync(Y, y_in, S * sizeof(float), hipMemcpyDeviceToDevice, stream);

  for (int l = 0; l < 2; ++l) {
    const size_t wo  = (size_t)l * DDIM * DDIM;
    const size_t bo  = (size_t)l * DDIM;
    const size_t f1o = (size_t)l * DDIM * FF;
    const size_t f2o = (size_t)l * FF * DDIM;
    const size_t fbo = (size_t)l * FF;

    // LN1
    ln_k<<<dim3(BT, 2), 64, 0, stream>>>(X, Y, ln1xg + bo, ln1xb + bo,
                                         ln1yg + bo, ln1yb + bo, xn, yn);
    // QKV: qx=yn@Wq kx=xn@Wk vx=xn@Wv qy=xn@Wq ky=yn@Wk vy=yn@Wv
    {
      GemmArgs a = {}; a.K = DDIM; a.N = DDIM; a.gelu = 0;
      a.p[0] = {yn, Wq + wo, nullptr, nullptr, qx};
      a.p[1] = {xn, Wk + wo, nullptr, nullptr, kx};
      a.p[2] = {xn, Wv + wo, nullptr, nullptr, vx};
      a.p[3] = {xn, Wq + wo, nullptr, nullptr, qy};
      a.p[4] = {yn, Wk + wo, nullptr, nullptr, ky};
      a.p[5] = {yn, Wv + wo, nullptr, nullptr, vy};
      gemm_k<<<dim3(2, BT / 64, 6), 256, 0, stream>>>(a);
    }
    // fused attention -> ob1, ob2
    attn_k<<<dim3(TT / 64, BB * HH), 256, 0, stream>>>(qx, kx, vx, qy, ky, vy, ob1, ob2);
    // output proj + residual
    {
      GemmArgs a = {}; a.K = DDIM; a.N = DDIM; a.gelu = 0;
      a.p[0] = {ob1, Wox + wo, box + bo, X, X};
      a.p[1] = {ob2, Woy + wo, boy + bo, Y, Y};
      gemm_k<<<dim3(2, BT / 64, 2), 256, 0, stream>>>(a);
    }
    // LN2
    ln_k<<<dim3(BT, 2), 64, 0, stream>>>(X, Y, ln2xg + bo, ln2xb + bo,
                                         ln2yg + bo, ln2yb + bo, xn, yn);
    // FFN1 + gelu
    {
      GemmArgs a = {}; a.K = DDIM; a.N = FF; a.gelu = 1;
      a.p[0] = {xn, fxw1 + f1o, fxb1 + fbo, nullptr, hx};
      a.p[1] = {yn, fyw1 + f1o, fyb1 + fbo, nullptr, hy};
      gemm_k<<<dim3(4, BT / 64, 2), 256, 0, stream>>>(a);
    }
    // FFN2 + residual
    {
      GemmArgs a = {}; a.K = FF; a.N = DDIM; a.gelu = 0;
      a.p[0] = {hx, fxw2 + f2o, fxb2 + bo, X, X};
      a.p[1] = {hy, fyw2 + f2o, fyb2 + bo, Y, Y};
      gemm_k<<<dim3(2, BT / 64, 2), 256, 0, stream>>>(a);
    }
  }
}

// Round 2
// 443.990 us; speedup vs baseline: 1.4999x; 1.4999x over previous
//
#include <hip/hip_runtime.h>
#include <cstddef>

#define BB   8
#define TT   1024
#define DDIM 128
#define HH   8
#define DHH  16
#define FF   256
#define BT   (BB * TT)   // 8192

typedef __attribute__((ext_vector_type(8))) short short8;
typedef __attribute__((ext_vector_type(4))) float f32x4;

__device__ __forceinline__ unsigned short bf(float x) {
  unsigned u = __builtin_bit_cast(unsigned, x);
  u += 0x7fffu + ((u >> 16) & 1u);   // RTN-even
  return (unsigned short)(u >> 16);
}

// ---------------------------------------------------------------------------
// LayerNorm: one 64-thread wave per row of 128. blockIdx.y selects x/y tensor.
// ---------------------------------------------------------------------------
__global__ __launch_bounds__(64) void ln_k(const float* __restrict__ X,
                                           const float* __restrict__ Y,
                                           const float* __restrict__ gx,
                                           const float* __restrict__ bx,
                                           const float* __restrict__ gy,
                                           const float* __restrict__ by,
                                           float* __restrict__ ox,
                                           float* __restrict__ oy) {
  const int row = blockIdx.x;
  const int which = blockIdx.y;
  const float* in = which ? Y : X;
  const float* g  = which ? gy : gx;
  const float* b  = which ? by : bx;
  float* out      = which ? oy : ox;
  const int tid = threadIdx.x;

  float2 v = *(const float2*)(in + (size_t)row * DDIM + tid * 2);
  float s  = v.x + v.y;
  float sq = v.x * v.x + v.y * v.y;
  #pragma unroll
  for (int off = 32; off >= 1; off >>= 1) {
    s  += __shfl_xor(s, off);
    sq += __shfl_xor(sq, off);
  }
  const float mean = s * (1.0f / DDIM);
  const float var  = sq * (1.0f / DDIM) - mean * mean;
  const float r    = rsqrtf(var + 1e-5f);

  float2 gg = *(const float2*)(g + tid * 2);
  float2 bb = *(const float2*)(b + tid * 2);
  float2 o;
  o.x = (v.x - mean) * r * gg.x + bb.x;
  o.y = (v.y - mean) * r * gg.y + bb.y;
  *(float2*)(out + (size_t)row * DDIM + tid * 2) = o;
}

// ---------------------------------------------------------------------------
// Generic batched GEMM: C = A(M,K) @ W(K,N) [+bias] [gelu] [+res]
// 64x64 tile / block, 256 threads, 4x4 micro-tile, BK=32.  (fp32 vector)
// ---------------------------------------------------------------------------
struct GemmP { const float* A; const float* W; const float* bias; const float* res; float* C; };
struct GemmArgs { GemmP p[6]; int K; int N; int gelu; };

__global__ __launch_bounds__(256) void gemm_k(GemmArgs a) {
  const GemmP pp = a.p[blockIdx.z];
  const int K = a.K, N = a.N;
  const int n0 = blockIdx.x * 64, m0 = blockIdx.y * 64;
  __shared__ float As[32][68];   // As[k][m] (transposed), padded
  __shared__ float Bs[32][68];   // Bs[k][n], padded
  const int tid = threadIdx.x;
  const int ty = tid >> 4, tx = tid & 15;
  float acc[4][4] = {};

  for (int k0 = 0; k0 < K; k0 += 32) {
    #pragma unroll
    for (int t = tid; t < 512; t += 256) {
      const int row = t >> 3, c4 = (t & 7) << 2;
      float4 v = *(const float4*)(pp.A + (size_t)(m0 + row) * K + k0 + c4);
      As[c4 + 0][row] = v.x; As[c4 + 1][row] = v.y;
      As[c4 + 2][row] = v.z; As[c4 + 3][row] = v.w;
    }
    #pragma unroll
    for (int t = tid; t < 512; t += 256) {
      const int row = t >> 4, c4 = (t & 15) << 2;
      *(float4*)&Bs[row][c4] = *(const float4*)(pp.W + (size_t)(k0 + row) * N + n0 + c4);
    }
    __syncthreads();
    #pragma unroll
    for (int k = 0; k < 32; ++k) {
      const float4 a4 = *(const float4*)&As[k][ty << 2];
      const float4 b4 = *(const float4*)&Bs[k][tx << 2];
      const float av[4] = {a4.x, a4.y, a4.z, a4.w};
      const float bv[4] = {b4.x, b4.y, b4.z, b4.w};
      #pragma unroll
      for (int i = 0; i < 4; ++i)
        #pragma unroll
        for (int j = 0; j < 4; ++j)
          acc[i][j] = fmaf(av[i], bv[j], acc[i][j]);
    }
    __syncthreads();
  }

  #pragma unroll
  for (int i = 0; i < 4; ++i) {
    const int m = m0 + (ty << 2) + i;
    #pragma unroll
    for (int j = 0; j < 4; ++j) {
      const int n = n0 + (tx << 2) + j;
      float v = acc[i][j];
      if (pp.bias) v += pp.bias[n];
      if (a.gelu) v = 0.5f * v * (1.0f + erff(v * 0.70710678118654752f));
      if (pp.res) v += pp.res[(size_t)m * N + n];
      pp.C[(size_t)m * N + n] = v;
    }
  }
}

// ---------------------------------------------------------------------------
// MFMA flash attention, both branches share one softmax:
//   S = [qx|qy] . [kx|ky]^T * 0.125   (d_qk = 32 -> one 16x16x32 MFMA / tile)
//   O = softmax(S) @ [vx|vy]          (d_v = 32, split cols -> o1, o2)
// Block = 256 threads = 4 waves; wave w owns 16 query rows; 16 key tiles of 64.
// Q A-frags in registers (bf16); K row-major LDS; V transposed LDS; P via LDS.
// ---------------------------------------------------------------------------
__global__ __launch_bounds__(256) void attn_k(const float* __restrict__ qx,
                                              const float* __restrict__ kx,
                                              const float* __restrict__ vx,
                                              const float* __restrict__ qy,
                                              const float* __restrict__ ky,
                                              const float* __restrict__ vy,
                                              float* __restrict__ o1,
                                              float* __restrict__ o2) {
  const int t0 = blockIdx.x * 64;
  const int bh = blockIdx.y;
  const int b = bh >> 3, h = bh & 7;
  const size_t base = (size_t)b * TT * DDIM + h * DHH;

  __shared__ __align__(16) unsigned short Ks[64][40];  // [s][d0..31], pad 8
  __shared__ __align__(16) unsigned short Vt[32][72];  // [c][s0..63], pad 8
  __shared__ __align__(16) unsigned short Ps[64][72];  // [q][s0..63], pad 8

  const int tid  = threadIdx.x;
  const int w    = tid >> 6;        // wave id 0..3
  const int lane = tid & 63;
  const int l15  = lane & 15;
  const int quad = lane >> 4;

  // ---- Q A-fragment (row m = l15, k = quad*8 + j), bf16, lives all block ----
  short8 qa;
  {
    const float* qp = (quad < 2) ? qx : qy;
    const int dq = (quad & 1) * 8;
    const size_t off = base + (size_t)(t0 + w * 16 + l15) * DDIM + dq;
    float4 q0 = *(const float4*)(qp + off);
    float4 q1 = *(const float4*)(qp + off + 4);
    qa[0] = (short)bf(q0.x); qa[1] = (short)bf(q0.y);
    qa[2] = (short)bf(q0.z); qa[3] = (short)bf(q0.w);
    qa[4] = (short)bf(q1.x); qa[5] = (short)bf(q1.y);
    qa[6] = (short)bf(q1.z); qa[7] = (short)bf(q1.w);
  }

  f32x4 Of0 = {0.f, 0.f, 0.f, 0.f};
  f32x4 Of1 = {0.f, 0.f, 0.f, 0.f};
  float m_i[4] = {-1e30f, -1e30f, -1e30f, -1e30f};
  float l_i[4] = {0.f, 0.f, 0.f, 0.f};

  for (int kt = 0; kt < TT / 64; ++kt) {
    const int s0 = kt * 64;

    // ---- stage K (row-major) ----
    #pragma unroll
    for (int t = tid; t < 512; t += 256) {
      const int s = t >> 3, g = t & 7;
      const float* kp = (g < 4) ? kx : ky;
      const int d4 = (g & 3) << 2;
      float4 v = *(const float4*)(kp + base + (size_t)(s0 + s) * DDIM + d4);
      ushort4 kb4; kb4.x = bf(v.x); kb4.y = bf(v.y); kb4.z = bf(v.z); kb4.w = bf(v.w);
      *(ushort4*)&Ks[s][(g < 4 ? 0 : 16) + d4] = kb4;
    }
    // ---- stage V transposed: Vt[c][s] ----
    #pragma unroll
    for (int t = tid; t < 512; t += 256) {
      const int c = t & 31;
      const int sb = (t >> 5) << 2;          // 0..60 step 4
      const float* vp = (c < 16) ? vx : vy;
      const int cc = c & 15;
      const size_t ro = base + (size_t)(s0 + sb) * DDIM + cc;
      ushort4 w4;
      w4.x = bf(vp[ro]);
      w4.y = bf(vp[ro + DDIM]);
      w4.z = bf(vp[ro + 2 * DDIM]);
      w4.w = bf(vp[ro + 3 * DDIM]);
      *(ushort4*)&Vt[c][sb] = w4;
    }
    __syncthreads();

    // ---- S = Q'.K'^T : 4 MFMAs (col tiles of 16) ----
    f32x4 Sf[4];
    #pragma unroll
    for (int t = 0; t < 4; ++t) {
      short8 kb = *(const short8*)&Ks[t * 16 + l15][quad * 8];
      f32x4 z = {0.f, 0.f, 0.f, 0.f};
      Sf[t] = __builtin_amdgcn_mfma_f32_16x16x32_bf16(qa, kb, z, 0, 0, 0);
    }

    // ---- online softmax per row (row = quad*4 + reg), cols over 16 lanes x 4 frags
    float al[4];
    #pragma unroll
    for (int reg = 0; reg < 4; ++reg) {
      float v0 = Sf[0][reg] * 0.125f, v1 = Sf[1][reg] * 0.125f;
      float v2 = Sf[2][reg] * 0.125f, v3 = Sf[3][reg] * 0.125f;
      float mx = fmaxf(fmaxf(v0, v1), fmaxf(v2, v3));
      #pragma unroll
      for (int off = 8; off >= 1; off >>= 1) mx = fmaxf(mx, __shfl_xor(mx, off, 16));
      const float mn = fmaxf(m_i[reg], mx);
      const float a  = __expf(m_i[reg] - mn);
      m_i[reg] = mn;
      const float p0 = __expf(v0 - mn), p1 = __expf(v1 - mn);
      const float p2 = __expf(v2 - mn), p3 = __expf(v3 - mn);
      float rs = p0 + p1 + p2 + p3;
      #pragma unroll
      for (int off = 8; off >= 1; off >>= 1) rs += __shfl_xor(rs, off, 16);
      l_i[reg] = l_i[reg] * a + rs;
      al[reg] = a;
      const int q = w * 16 + quad * 4 + reg;
      Ps[q][l15]      = bf(p0);
      Ps[q][16 + l15] = bf(p1);
      Ps[q][32 + l15] = bf(p2);
      Ps[q][48 + l15] = bf(p3);
    }

    #pragma unroll
    for (int reg = 0; reg < 4; ++reg) { Of0[reg] *= al[reg]; Of1[reg] *= al[reg]; }

    // ---- O += P @ V' : A-frag from Ps (own wave's rows), B-frag from Vt ----
    #pragma unroll
    for (int sh = 0; sh < 2; ++sh) {
      short8 pa  = *(const short8*)&Ps[w * 16 + l15][sh * 32 + quad * 8];
      short8 vb0 = *(const short8*)&Vt[l15][sh * 32 + quad * 8];
      short8 vb1 = *(const short8*)&Vt[16 + l15][sh * 32 + quad * 8];
      Of0 = __builtin_amdgcn_mfma_f32_16x16x32_bf16(pa, vb0, Of0, 0, 0, 0);
      Of1 = __builtin_amdgcn_mfma_f32_16x16x32_bf16(pa, vb1, Of1, 0, 0, 0);
    }
    __syncthreads();
  }

  // ---- epilogue: normalize + split cols into o1 (0..15) / o2 (16..31) ----
  #pragma unroll
  for (int reg = 0; reg < 4; ++reg) {
    const float inv = 1.0f / l_i[reg];
    const size_t r = base + (size_t)(t0 + w * 16 + quad * 4 + reg) * DDIM + l15;
    o1[r] = Of0[reg] * inv;
    o2[r] = Of1[reg] * inv;
  }
}

// ---------------------------------------------------------------------------
extern "C" void kernel_launch(void* const* d_in, const int* in_sizes, int n_in,
                              void* d_out, int out_size, void* d_ws, size_t ws_size,
                              hipStream_t stream) {
  const float* x_in  = (const float*)d_in[0];
  const float* y_in  = (const float*)d_in[1];
  const float* Wq    = (const float*)d_in[2];
  const float* Wk    = (const float*)d_in[3];
  const float* Wv    = (const float*)d_in[4];
  const float* Wox   = (const float*)d_in[5];
  const float* box   = (const float*)d_in[6];
  const float* Woy   = (const float*)d_in[7];
  const float* boy   = (const float*)d_in[8];
  const float* ln1xg = (const float*)d_in[9];
  const float* ln1xb = (const float*)d_in[10];
  const float* ln1yg = (const float*)d_in[11];
  const float* ln1yb = (const float*)d_in[12];
  const float* ln2xg = (const float*)d_in[13];
  const float* ln2xb = (const float*)d_in[14];
  const float* ln2yg = (const float*)d_in[15];
  const float* ln2yb = (const float*)d_in[16];
  const float* fxw1  = (const float*)d_in[17];
  const float* fxb1  = (const float*)d_in[18];
  const float* fxw2  = (const float*)d_in[19];
  const float* fxb2  = (const float*)d_in[20];
  const float* fyw1  = (const float*)d_in[21];
  const float* fyb1  = (const float*)d_in[22];
  const float* fyw2  = (const float*)d_in[23];
  const float* fyb2  = (const float*)d_in[24];

  const size_t S = (size_t)BT * DDIM;  // 1M floats
  float* X = (float*)d_out;
  float* Y = X + S;
  float* w  = (float*)d_ws;
  float* xn = w + 0 * S;
  float* yn = w + 1 * S;
  float* qx = w + 2 * S;
  float* kx = w + 3 * S;
  float* vx = w + 4 * S;
  float* qy = w + 5 * S;
  float* ky = w + 6 * S;
  float* vy = w + 7 * S;
  float* ob1 = w + 8 * S;
  float* ob2 = w + 9 * S;
  float* hx = w + 2 * S;   // reuse qx/kx after attention (2S floats)
  float* hy = w + 4 * S;   // reuse vx/qy after attention

  hipMemcpyAsync(X, x_in, S * sizeof(float), hipMemcpyDeviceToDevice, stream);
  hipMemcpyAsync(Y, y_in, S * sizeof(float), hipMemcpyDeviceToDevice, stream);

  for (int l = 0; l < 2; ++l) {
    const size_t wo  = (size_t)l * DDIM * DDIM;
    const size_t bo  = (size_t)l * DDIM;
    const size_t f1o = (size_t)l * DDIM * FF;
    const size_t f2o = (size_t)l * FF * DDIM;
    const size_t fbo = (size_t)l * FF;

    // LN1
    ln_k<<<dim3(BT, 2), 64, 0, stream>>>(X, Y, ln1xg + bo, ln1xb + bo,
                                         ln1yg + bo, ln1yb + bo, xn, yn);
    // QKV: qx=yn@Wq kx=xn@Wk vx=xn@Wv qy=xn@Wq ky=yn@Wk vy=yn@Wv
    {
      GemmArgs a = {}; a.K = DDIM; a.N = DDIM; a.gelu = 0;
      a.p[0] = {yn, Wq + wo, nullptr, nullptr, qx};
      a.p[1] = {xn, Wk + wo, nullptr, nullptr, kx};
      a.p[2] = {xn, Wv + wo, nullptr, nullptr, vx};
      a.p[3] = {xn, Wq + wo, nullptr, nullptr, qy};
      a.p[4] = {yn, Wk + wo, nullptr, nullptr, ky};
      a.p[5] = {yn, Wv + wo, nullptr, nullptr, vy};
      gemm_k<<<dim3(2, BT / 64, 6), 256, 0, stream>>>(a);
    }
    // fused attention -> ob1, ob2
    attn_k<<<dim3(TT / 64, BB * HH), 256, 0, stream>>>(qx, kx, vx, qy, ky, vy, ob1, ob2);
    // output proj + residual
    {
      GemmArgs a = {}; a.K = DDIM; a.N = DDIM; a.gelu = 0;
      a.p[0] = {ob1, Wox + wo, box + bo, X, X};
      a.p[1] = {ob2, Woy + wo, boy + bo, Y, Y};
      gemm_k<<<dim3(2, BT / 64, 2), 256, 0, stream>>>(a);
    }
    // LN2
    ln_k<<<dim3(BT, 2), 64, 0, stream>>>(X, Y, ln2xg + bo, ln2xb + bo,
                                         ln2yg + bo, ln2yb + bo, xn, yn);
    // FFN1 + gelu
    {
      GemmArgs a = {}; a.K = DDIM; a.N = FF; a.gelu = 1;
      a.p[0] = {xn, fxw1 + f1o, fxb1 + fbo, nullptr, hx};
      a.p[1] = {yn, fyw1 + f1o, fyb1 + fbo, nullptr, hy};
      gemm_k<<<dim3(4, BT / 64, 2), 256, 0, stream>>>(a);
    }
    // FFN2 + residual
    {
      GemmArgs a = {}; a.K = FF; a.N = DDIM; a.gelu = 0;
      a.p[0] = {hx, fxw2 + f2o, fxb2 + bo, X, X};
      a.p[1] = {hy, fyw2 + f2o, fyb2 + bo, Y, Y};
      gemm_k<<<dim3(2, BT / 64, 2), 256, 0, stream>>>(a);
    }
  }
}

// Round 3
// 425.262 us; speedup vs baseline: 1.5659x; 1.0440x over previous
//
#include <hip/hip_runtime.h>
#include <cstddef>

#define BB   8
#define TT   1024
#define DDIM 128
#define HH   8
#define DHH  16
#define FF   256
#define BT   (BB * TT)   // 8192

typedef unsigned short u16;
typedef __attribute__((ext_vector_type(8))) short short8;
typedef __attribute__((ext_vector_type(4))) float f32x4;

__device__ __forceinline__ u16 bf(float x) {
  unsigned u = __builtin_bit_cast(unsigned, x);
  u += 0x7fffu + ((u >> 16) & 1u);   // RTN-even
  return (u16)(u >> 16);
}

// ---------------------------------------------------------------------------
// Weight prep: fp32 (K,N) -> bf16 (N,K)  (transpose + convert), 18 matrices.
// ---------------------------------------------------------------------------
struct PrepP { const float* W; u16* Wt; int K; int N; };
struct PrepArgs { PrepP p[18]; };

__global__ __launch_bounds__(256) void prep_k(PrepArgs a) {
  const PrepP pp = a.p[blockIdx.z];
  const int n0 = blockIdx.x * 64, k0 = blockIdx.y * 64;
  if (n0 >= pp.N || k0 >= pp.K) return;
  __shared__ float tile[64][65];
  const int tid = threadIdx.x;
  #pragma unroll
  for (int t = tid; t < 1024; t += 256) {
    const int kk = t >> 4, nn4 = (t & 15) << 2;
    float4 v = *(const float4*)(pp.W + (size_t)(k0 + kk) * pp.N + n0 + nn4);
    tile[nn4 + 0][kk] = v.x; tile[nn4 + 1][kk] = v.y;
    tile[nn4 + 2][kk] = v.z; tile[nn4 + 3][kk] = v.w;
  }
  __syncthreads();
  #pragma unroll
  for (int t = tid; t < 1024; t += 256) {
    const int nn = t >> 4, kk4 = (t & 15) << 2;
    ushort4 o;
    o.x = bf(tile[nn][kk4 + 0]); o.y = bf(tile[nn][kk4 + 1]);
    o.z = bf(tile[nn][kk4 + 2]); o.w = bf(tile[nn][kk4 + 3]);
    *(ushort4*)(pp.Wt + (size_t)(n0 + nn) * pp.K + k0 + kk4) = o;
  }
}

// ---------------------------------------------------------------------------
// LayerNorm: one wave per row of 128; fp32 in, bf16 out.
// ---------------------------------------------------------------------------
__global__ __launch_bounds__(64) void ln_k(const float* __restrict__ X,
                                           const float* __restrict__ Y,
                                           const float* __restrict__ gx,
                                           const float* __restrict__ bx,
                                           const float* __restrict__ gy,
                                           const float* __restrict__ by,
                                           u16* __restrict__ ox,
                                           u16* __restrict__ oy) {
  const int row = blockIdx.x;
  const int which = blockIdx.y;
  const float* in = which ? Y : X;
  const float* g  = which ? gy : gx;
  const float* b  = which ? by : bx;
  u16* out        = which ? oy : ox;
  const int tid = threadIdx.x;

  float2 v = *(const float2*)(in + (size_t)row * DDIM + tid * 2);
  float s  = v.x + v.y;
  float sq = v.x * v.x + v.y * v.y;
  #pragma unroll
  for (int off = 32; off >= 1; off >>= 1) {
    s  += __shfl_xor(s, off);
    sq += __shfl_xor(sq, off);
  }
  const float mean = s * (1.0f / DDIM);
  const float var  = sq * (1.0f / DDIM) - mean * mean;
  const float r    = rsqrtf(var + 1e-5f);

  float2 gg = *(const float2*)(g + tid * 2);
  float2 bb = *(const float2*)(b + tid * 2);
  ushort2 o;
  o.x = bf((v.x - mean) * r * gg.x + bb.x);
  o.y = bf((v.y - mean) * r * gg.y + bb.y);
  *(ushort2*)(out + (size_t)row * DDIM + tid * 2) = o;
}

// ---------------------------------------------------------------------------
// bf16 MFMA GEMM: C = A(M,K)bf16 @ Wt(N,K)bf16 [+bias][gelu][+res(fp32)]
// 128x128 tile, 256 threads = 4 waves (64x64 quadrant each), BK=64.
// ---------------------------------------------------------------------------
struct GemmP { const u16* A; const u16* Wt; const float* bias; const float* res; void* C; };
struct GemmArgs { GemmP p[6]; int K; int N; int gelu; int bf16out; };

__global__ __launch_bounds__(256) void gemm_k(GemmArgs a) {
  const GemmP pp = a.p[blockIdx.z];
  const int K = a.K, N = a.N;
  const int n0 = blockIdx.x * 128, m0 = blockIdx.y * 128;
  __shared__ __align__(16) u16 As[128][72];
  __shared__ __align__(16) u16 Bs[128][72];
  const int tid  = threadIdx.x;
  const int w    = tid >> 6;
  const int lane = tid & 63;
  const int l15  = lane & 15;
  const int quad = lane >> 4;
  const int wr = w >> 1, wc = w & 1;

  f32x4 acc[4][4];
  #pragma unroll
  for (int i = 0; i < 4; ++i)
    #pragma unroll
    for (int j = 0; j < 4; ++j) acc[i][j] = {0.f, 0.f, 0.f, 0.f};

  for (int k0 = 0; k0 < K; k0 += 64) {
    #pragma unroll
    for (int t = tid; t < 1024; t += 256) {
      const int row = t >> 3, c8 = (t & 7) << 3;
      *(short8*)&As[row][c8] = *(const short8*)(pp.A + (size_t)(m0 + row) * K + k0 + c8);
    }
    #pragma unroll
    for (int t = tid; t < 1024; t += 256) {
      const int row = t >> 3, c8 = (t & 7) << 3;
      *(short8*)&Bs[row][c8] = *(const short8*)(pp.Wt + (size_t)(n0 + row) * K + k0 + c8);
    }
    __syncthreads();
    #pragma unroll
    for (int ks = 0; ks < 2; ++ks) {
      short8 ar[4], br[4];
      #pragma unroll
      for (int i = 0; i < 4; ++i)
        ar[i] = *(const short8*)&As[wr * 64 + i * 16 + l15][ks * 32 + quad * 8];
      #pragma unroll
      for (int j = 0; j < 4; ++j)
        br[j] = *(const short8*)&Bs[wc * 64 + j * 16 + l15][ks * 32 + quad * 8];
      #pragma unroll
      for (int i = 0; i < 4; ++i)
        #pragma unroll
        for (int j = 0; j < 4; ++j)
          acc[i][j] = __builtin_amdgcn_mfma_f32_16x16x32_bf16(ar[i], br[j], acc[i][j], 0, 0, 0);
    }
    __syncthreads();
  }

  #pragma unroll
  for (int i = 0; i < 4; ++i) {
    #pragma unroll
    for (int j = 0; j < 4; ++j) {
      const int n = n0 + wc * 64 + j * 16 + l15;
      #pragma unroll
      for (int reg = 0; reg < 4; ++reg) {
        const int m = m0 + wr * 64 + i * 16 + quad * 4 + reg;
        float v = acc[i][j][reg];
        if (pp.bias) v += pp.bias[n];
        if (a.gelu) v = 0.5f * v * (1.0f + erff(v * 0.70710678118654752f));
        if (pp.res) v += pp.res[(size_t)m * N + n];
        if (a.bf16out) ((u16*)pp.C)[(size_t)m * N + n] = bf(v);
        else           ((float*)pp.C)[(size_t)m * N + n] = v;
      }
    }
  }
}

// ---------------------------------------------------------------------------
// MFMA flash attention (shared softmax), bf16 I/O, no-max softmax,
// lane-local denominator accumulation (reduced once at the end).
// ---------------------------------------------------------------------------
__global__ __launch_bounds__(256) void attn_k(const u16* __restrict__ qx,
                                              const u16* __restrict__ kx,
                                              const u16* __restrict__ vx,
                                              const u16* __restrict__ qy,
                                              const u16* __restrict__ ky,
                                              const u16* __restrict__ vy,
                                              u16* __restrict__ o1,
                                              u16* __restrict__ o2) {
  const int t0 = blockIdx.x * 64;
  const int bh = blockIdx.y;
  const int b = bh >> 3, h = bh & 7;
  const size_t base = (size_t)b * TT * DDIM + h * DHH;

  __shared__ __align__(16) u16 Ks[64][40];  // [s][d0..31]
  __shared__ __align__(16) u16 Vt[32][72];  // [c][s0..63]
  __shared__ __align__(16) u16 Ps[64][72];  // [q][s0..63]

  const int tid  = threadIdx.x;
  const int w    = tid >> 6;
  const int lane = tid & 63;
  const int l15  = lane & 15;
  const int quad = lane >> 4;

  // Q A-fragment (row m = l15, k = quad*8+j): direct bf16 16B load
  const u16* qp = (quad < 2) ? qx : qy;
  const int dq = (quad & 1) * 8;
  const short8 qa = *(const short8*)(qp + base + (size_t)(t0 + w * 16 + l15) * DDIM + dq);

  f32x4 Of0 = {0.f, 0.f, 0.f, 0.f};
  f32x4 Of1 = {0.f, 0.f, 0.f, 0.f};
  float l_i[4] = {0.f, 0.f, 0.f, 0.f};

  for (int kt = 0; kt < TT / 64; ++kt) {
    const int s0 = kt * 64;

    // stage K: 256 x 16B chunks, one per thread
    {
      const int s = tid >> 2, c = tid & 3;
      const u16* kp = (c < 2) ? kx : ky;
      const int d8 = (c & 1) * 8;
      *(short8*)&Ks[s][(c < 2 ? 0 : 16) + d8] =
          *(const short8*)(kp + base + (size_t)(s0 + s) * DDIM + d8);
    }
    // stage V transposed: Vt[c][s]
    #pragma unroll
    for (int t = tid; t < 512; t += 256) {
      const int c = t & 31;
      const int sb = (t >> 5) << 2;
      const u16* vp = (c < 16) ? vx : vy;
      const int cc = c & 15;
      const size_t ro = base + (size_t)(s0 + sb) * DDIM + cc;
      ushort4 w4;
      w4.x = vp[ro];
      w4.y = vp[ro + DDIM];
      w4.z = vp[ro + 2 * DDIM];
      w4.w = vp[ro + 3 * DDIM];
      *(ushort4*)&Vt[c][sb] = w4;
    }
    __syncthreads();

    // S = Q'.K'^T : 4 MFMAs
    f32x4 Sf[4];
    #pragma unroll
    for (int t = 0; t < 4; ++t) {
      short8 kb = *(const short8*)&Ks[t * 16 + l15][quad * 8];
      f32x4 z = {0.f, 0.f, 0.f, 0.f};
      Sf[t] = __builtin_amdgcn_mfma_f32_16x16x32_bf16(qa, kb, z, 0, 0, 0);
    }

    // exp (no max subtraction: |S*0.125| << 88 for LN'd inputs), lane-local sums
    #pragma unroll
    for (int reg = 0; reg < 4; ++reg) {
      const float p0 = __expf(Sf[0][reg] * 0.125f);
      const float p1 = __expf(Sf[1][reg] * 0.125f);
      const float p2 = __expf(Sf[2][reg] * 0.125f);
      const float p3 = __expf(Sf[3][reg] * 0.125f);
      l_i[reg] += p0 + p1 + p2 + p3;
      const int q = w * 16 + quad * 4 + reg;
      Ps[q][l15]      = bf(p0);
      Ps[q][16 + l15] = bf(p1);
      Ps[q][32 + l15] = bf(p2);
      Ps[q][48 + l15] = bf(p3);
    }

    // O += P @ V'
    #pragma unroll
    for (int sh = 0; sh < 2; ++sh) {
      short8 pa  = *(const short8*)&Ps[w * 16 + l15][sh * 32 + quad * 8];
      short8 vb0 = *(const short8*)&Vt[l15][sh * 32 + quad * 8];
      short8 vb1 = *(const short8*)&Vt[16 + l15][sh * 32 + quad * 8];
      Of0 = __builtin_amdgcn_mfma_f32_16x16x32_bf16(pa, vb0, Of0, 0, 0, 0);
      Of1 = __builtin_amdgcn_mfma_f32_16x16x32_bf16(pa, vb1, Of1, 0, 0, 0);
    }
    __syncthreads();
  }

  // reduce denominators across the 16 lanes sharing a row, then write bf16
  #pragma unroll
  for (int reg = 0; reg < 4; ++reg) {
    float l = l_i[reg];
    #pragma unroll
    for (int off = 8; off >= 1; off >>= 1) l += __shfl_xor(l, off, 16);
    const float inv = 1.0f / l;
    const size_t r = base + (size_t)(t0 + w * 16 + quad * 4 + reg) * DDIM + l15;
    o1[r] = bf(Of0[reg] * inv);
    o2[r] = bf(Of1[reg] * inv);
  }
}

// ---------------------------------------------------------------------------
extern "C" void kernel_launch(void* const* d_in, const int* in_sizes, int n_in,
                              void* d_out, int out_size, void* d_ws, size_t ws_size,
                              hipStream_t stream) {
  const float* x_in  = (const float*)d_in[0];
  const float* y_in  = (const float*)d_in[1];
  const float* Wq    = (const float*)d_in[2];
  const float* Wk    = (const float*)d_in[3];
  const float* Wv    = (const float*)d_in[4];
  const float* Wox   = (const float*)d_in[5];
  const float* box   = (const float*)d_in[6];
  const float* Woy   = (const float*)d_in[7];
  const float* boy   = (const float*)d_in[8];
  const float* ln1xg = (const float*)d_in[9];
  const float* ln1xb = (const float*)d_in[10];
  const float* ln1yg = (const float*)d_in[11];
  const float* ln1yb = (const float*)d_in[12];
  const float* ln2xg = (const float*)d_in[13];
  const float* ln2xb = (const float*)d_in[14];
  const float* ln2yg = (const float*)d_in[15];
  const float* ln2yb = (const float*)d_in[16];
  const float* fxw1  = (const float*)d_in[17];
  const float* fxb1  = (const float*)d_in[18];
  const float* fxw2  = (const float*)d_in[19];
  const float* fxb2  = (const float*)d_in[20];
  const float* fyw1  = (const float*)d_in[21];
  const float* fyb1  = (const float*)d_in[22];
  const float* fyw2  = (const float*)d_in[23];
  const float* fyb2  = (const float*)d_in[24];

  const size_t S = (size_t)BT * DDIM;  // 1,048,576 elems
  float* X = (float*)d_out;
  float* Y = X + S;

  char* wsb = (char*)d_ws;
  auto carve = [&](size_t bytes) { char* p = wsb; wsb += (bytes + 255) & ~(size_t)255; return p; };
  u16* xn  = (u16*)carve(S * 2);
  u16* yn  = (u16*)carve(S * 2);
  u16* qx  = (u16*)carve(S * 2);
  u16* kx  = (u16*)carve(S * 2);
  u16* vx  = (u16*)carve(S * 2);
  u16* qy  = (u16*)carve(S * 2);
  u16* ky  = (u16*)carve(S * 2);
  u16* vy  = (u16*)carve(S * 2);
  u16* ob1 = (u16*)carve(S * 2);
  u16* ob2 = (u16*)carve(S * 2);
  u16* hx  = (u16*)carve(2 * S * 2);
  u16* hy  = (u16*)carve(2 * S * 2);
  u16* WqT[2], *WkT[2], *WvT[2], *WoxT[2], *WoyT[2];
  u16* f1xT[2], *f1yT[2], *f2xT[2], *f2yT[2];
  for (int l = 0; l < 2; ++l) {
    WqT[l]  = (u16*)carve(16384 * 2);
    WkT[l]  = (u16*)carve(16384 * 2);
    WvT[l]  = (u16*)carve(16384 * 2);
    WoxT[l] = (u16*)carve(16384 * 2);
    WoyT[l] = (u16*)carve(16384 * 2);
    f1xT[l] = (u16*)carve(32768 * 2);
    f1yT[l] = (u16*)carve(32768 * 2);
    f2xT[l] = (u16*)carve(32768 * 2);
    f2yT[l] = (u16*)carve(32768 * 2);
  }

  // weight transpose+convert (all layers, one kernel)
  {
    PrepArgs a;
    int idx = 0;
    for (int l = 0; l < 2; ++l) {
      a.p[idx++] = {Wq  + (size_t)l * 16384, WqT[l],  128, 128};
      a.p[idx++] = {Wk  + (size_t)l * 16384, WkT[l],  128, 128};
      a.p[idx++] = {Wv  + (size_t)l * 16384, WvT[l],  128, 128};
      a.p[idx++] = {Wox + (size_t)l * 16384, WoxT[l], 128, 128};
      a.p[idx++] = {Woy + (size_t)l * 16384, WoyT[l], 128, 128};
      a.p[idx++] = {fxw1 + (size_t)l * 32768, f1xT[l], 128, 256};
      a.p[idx++] = {fyw1 + (size_t)l * 32768, f1yT[l], 128, 256};
      a.p[idx++] = {fxw2 + (size_t)l * 32768, f2xT[l], 256, 128};
      a.p[idx++] = {fyw2 + (size_t)l * 32768, f2yT[l], 256, 128};
    }
    prep_k<<<dim3(4, 4, 18), 256, 0, stream>>>(a);
  }

  hipMemcpyAsync(X, x_in, S * sizeof(float), hipMemcpyDeviceToDevice, stream);
  hipMemcpyAsync(Y, y_in, S * sizeof(float), hipMemcpyDeviceToDevice, stream);

  for (int l = 0; l < 2; ++l) {
    const size_t bo  = (size_t)l * DDIM;
    const size_t fbo = (size_t)l * FF;

    // LN1
    ln_k<<<dim3(BT, 2), 64, 0, stream>>>(X, Y, ln1xg + bo, ln1xb + bo,
                                         ln1yg + bo, ln1yb + bo, xn, yn);
    // QKV (6-way batched)
    {
      GemmArgs a = {}; a.K = DDIM; a.N = DDIM; a.gelu = 0; a.bf16out = 1;
      a.p[0] = {yn, WqT[l], nullptr, nullptr, qx};
      a.p[1] = {xn, WkT[l], nullptr, nullptr, kx};
      a.p[2] = {xn, WvT[l], nullptr, nullptr, vx};
      a.p[3] = {xn, WqT[l], nullptr, nullptr, qy};
      a.p[4] = {yn, WkT[l], nullptr, nullptr, ky};
      a.p[5] = {yn, WvT[l], nullptr, nullptr, vy};
      gemm_k<<<dim3(1, BT / 128, 6), 256, 0, stream>>>(a);
    }
    // fused attention
    attn_k<<<dim3(TT / 64, BB * HH), 256, 0, stream>>>(qx, kx, vx, qy, ky, vy, ob1, ob2);
    // output proj + residual (fp32 out)
    {
      GemmArgs a = {}; a.K = DDIM; a.N = DDIM; a.gelu = 0; a.bf16out = 0;
      a.p[0] = {ob1, WoxT[l], box + bo, X, X};
      a.p[1] = {ob2, WoyT[l], boy + bo, Y, Y};
      gemm_k<<<dim3(1, BT / 128, 2), 256, 0, stream>>>(a);
    }
    // LN2
    ln_k<<<dim3(BT, 2), 64, 0, stream>>>(X, Y, ln2xg + bo, ln2xb + bo,
                                         ln2yg + bo, ln2yb + bo, xn, yn);
    // FFN1 + gelu (bf16 out)
    {
      GemmArgs a = {}; a.K = DDIM; a.N = FF; a.gelu = 1; a.bf16out = 1;
      a.p[0] = {xn, f1xT[l], fxb1 + fbo, nullptr, hx};
      a.p[1] = {yn, f1yT[l], fyb1 + fbo, nullptr, hy};
      gemm_k<<<dim3(2, BT / 128, 2), 256, 0, stream>>>(a);
    }
    // FFN2 + residual (fp32 out)
    {
      GemmArgs a = {}; a.K = FF; a.N = DDIM; a.gelu = 0; a.bf16out = 0;
      a.p[0] = {hx, f2xT[l], fxb2 + bo, X, X};
      a.p[1] = {hy, f2yT[l], fyb2 + bo, Y, Y};
      gemm_k<<<dim3(1, BT / 128, 2), 256, 0, stream>>>(a);
    }
  }
}

// Round 4
// 308.039 us; speedup vs baseline: 2.1618x; 1.3805x over previous
//
#include <hip/hip_runtime.h>
#include <cstddef>

#define BB   8
#define TT   1024
#define DDIM 128
#define HH   8
#define DHH  16
#define FF   256
#define BT   (BB * TT)   // 8192

typedef unsigned short u16;
typedef __attribute__((ext_vector_type(8))) short short8;
typedef __attribute__((ext_vector_type(4))) float f32x4;

__device__ __forceinline__ u16 bf(float x) {
  unsigned u = __builtin_bit_cast(unsigned, x);
  u += 0x7fffu + ((u >> 16) & 1u);   // RTN-even
  return (u16)(u >> 16);
}

// fast gelu: 0.5x(1+tanh(0.79788456(x+0.044715x^3))) = x*sigmoid(2t)
__device__ __forceinline__ float gelu_f(float x) {
  const float t = x * (0.79788456f + 0.03567740814f * x * x);
  return x / (1.0f + __expf(-2.0f * t));
}

// ---------------------------------------------------------------------------
// Weight prep: fp32 (K,N) -> bf16 (N,K)  (transpose + convert), 18 matrices.
// ---------------------------------------------------------------------------
struct PrepP { const float* W; u16* Wt; int K; int N; };
struct PrepArgs { PrepP p[18]; };

__global__ __launch_bounds__(256) void prep_k(PrepArgs a) {
  const PrepP pp = a.p[blockIdx.z];
  const int n0 = blockIdx.x * 64, k0 = blockIdx.y * 64;
  if (n0 >= pp.N || k0 >= pp.K) return;
  __shared__ float tile[64][65];
  const int tid = threadIdx.x;
  #pragma unroll
  for (int t = tid; t < 1024; t += 256) {
    const int kk = t >> 4, nn4 = (t & 15) << 2;
    float4 v = *(const float4*)(pp.W + (size_t)(k0 + kk) * pp.N + n0 + nn4);
    tile[nn4 + 0][kk] = v.x; tile[nn4 + 1][kk] = v.y;
    tile[nn4 + 2][kk] = v.z; tile[nn4 + 3][kk] = v.w;
  }
  __syncthreads();
  #pragma unroll
  for (int t = tid; t < 1024; t += 256) {
    const int nn = t >> 4, kk4 = (t & 15) << 2;
    ushort4 o;
    o.x = bf(tile[nn][kk4 + 0]); o.y = bf(tile[nn][kk4 + 1]);
    o.z = bf(tile[nn][kk4 + 2]); o.w = bf(tile[nn][kk4 + 3]);
    *(ushort4*)(pp.Wt + (size_t)(n0 + nn) * pp.K + k0 + kk4) = o;
  }
}

// ---------------------------------------------------------------------------
// Standalone LN (layer-0 LN1 only): fp32 in -> bf16 out. 4 rows / 256-thr block.
// ---------------------------------------------------------------------------
__global__ __launch_bounds__(256) void ln0_k(const float* __restrict__ X,
                                             const float* __restrict__ Y,
                                             const float* __restrict__ gx,
                                             const float* __restrict__ bx,
                                             const float* __restrict__ gy,
                                             const float* __restrict__ by,
                                             u16* __restrict__ ox,
                                             u16* __restrict__ oy) {
  const int which = blockIdx.y;
  const float* in = which ? Y : X;
  const float* g  = which ? gy : gx;
  const float* b  = which ? by : bx;
  u16* out        = which ? oy : ox;
  const int row  = blockIdx.x * 4 + (threadIdx.x >> 6);
  const int lane = threadIdx.x & 63;

  float2 v = *(const float2*)(in + (size_t)row * DDIM + lane * 2);
  float s  = v.x + v.y;
  float sq = v.x * v.x + v.y * v.y;
  #pragma unroll
  for (int off = 32; off >= 1; off >>= 1) {
    s  += __shfl_xor(s, off);
    sq += __shfl_xor(sq, off);
  }
  const float mean = s * (1.0f / DDIM);
  const float var  = sq * (1.0f / DDIM) - mean * mean;
  const float r    = rsqrtf(var + 1e-5f);
  float2 gg = *(const float2*)(g + lane * 2);
  float2 bb = *(const float2*)(b + lane * 2);
  ushort2 o;
  o.x = bf((v.x - mean) * r * gg.x + bb.x);
  o.y = bf((v.y - mean) * r * gg.y + bb.y);
  *(ushort2*)(out + (size_t)row * DDIM + lane * 2) = o;
}

// ---------------------------------------------------------------------------
// bf16 MFMA GEMM with fused epilogue:
//   C = A(M,K)bf16 @ Wt(N,K)bf16  [+bias] [gelu] [+res fp32]
//   -> optional fp32 raw out (residual stream) and/or bf16 out;
//   if ln: also apply per-row LayerNorm (requires N==128, gridDim.x==1) and
//   write normalized bf16 to outB while raw goes to outF.
// Tile 64x128, 256 threads = 4 waves in 2x2 quadrants (32 rows x 64 cols).
// ---------------------------------------------------------------------------
struct GemmP { const u16* A; const u16* Wt; const float* bias; const float* res;
               float* outF; u16* outB; const float* g; const float* b; };
struct GemmArgs { GemmP p[6]; int K; int N; int gelu; int ln; };

__global__ __launch_bounds__(256) void gemmf_k(GemmArgs a) {
  const GemmP pp = a.p[blockIdx.z];
  const int K = a.K, N = a.N;
  const int n0 = blockIdx.x * 128, m0 = blockIdx.y * 64;
  __shared__ __align__(16) u16 As[64][72];
  __shared__ __align__(16) u16 Bs[128][72];
  __shared__ float2 stats[64][2];
  const int tid  = threadIdx.x;
  const int w    = tid >> 6;
  const int lane = tid & 63;
  const int l15  = lane & 15;
  const int quad = lane >> 4;
  const int wr = w >> 1, wc = w & 1;

  f32x4 acc[2][4];
  #pragma unroll
  for (int i = 0; i < 2; ++i)
    #pragma unroll
    for (int j = 0; j < 4; ++j) acc[i][j] = {0.f, 0.f, 0.f, 0.f};

  for (int k0 = 0; k0 < K; k0 += 64) {
    #pragma unroll
    for (int t = tid; t < 512; t += 256) {
      const int row = t >> 3, c8 = (t & 7) << 3;
      *(short8*)&As[row][c8] = *(const short8*)(pp.A + (size_t)(m0 + row) * K + k0 + c8);
    }
    #pragma unroll
    for (int t = tid; t < 1024; t += 256) {
      const int row = t >> 3, c8 = (t & 7) << 3;
      *(short8*)&Bs[row][c8] = *(const short8*)(pp.Wt + (size_t)(n0 + row) * K + k0 + c8);
    }
    __syncthreads();
    #pragma unroll
    for (int ks = 0; ks < 2; ++ks) {
      short8 ar[2], br[4];
      #pragma unroll
      for (int i = 0; i < 2; ++i)
        ar[i] = *(const short8*)&As[wr * 32 + i * 16 + l15][ks * 32 + quad * 8];
      #pragma unroll
      for (int j = 0; j < 4; ++j)
        br[j] = *(const short8*)&Bs[wc * 64 + j * 16 + l15][ks * 32 + quad * 8];
      #pragma unroll
      for (int i = 0; i < 2; ++i)
        #pragma unroll
        for (int j = 0; j < 4; ++j)
          acc[i][j] = __builtin_amdgcn_mfma_f32_16x16x32_bf16(ar[i], br[j], acc[i][j], 0, 0, 0);
    }
    __syncthreads();
  }

  // ---- epilogue: bias / gelu / res, raw fp32 store ----
  #pragma unroll
  for (int i = 0; i < 2; ++i) {
    #pragma unroll
    for (int j = 0; j < 4; ++j) {
      const int n = n0 + wc * 64 + j * 16 + l15;
      const float bias_v = pp.bias ? pp.bias[n] : 0.f;
      #pragma unroll
      for (int reg = 0; reg < 4; ++reg) {
        const int m = m0 + wr * 32 + i * 16 + quad * 4 + reg;
        float v = acc[i][j][reg] + bias_v;
        if (a.gelu) v = gelu_f(v);
        if (pp.res) v += pp.res[(size_t)m * N + n];
        acc[i][j][reg] = v;
        if (pp.outF) pp.outF[(size_t)m * N + n] = v;
      }
    }
  }

  if (!a.ln) {
    if (pp.outB) {
      #pragma unroll
      for (int i = 0; i < 2; ++i)
        #pragma unroll
        for (int j = 0; j < 4; ++j) {
          const int n = n0 + wc * 64 + j * 16 + l15;
          #pragma unroll
          for (int reg = 0; reg < 4; ++reg) {
            const int m = m0 + wr * 32 + i * 16 + quad * 4 + reg;
            pp.outB[(size_t)m * N + n] = bf(acc[i][j][reg]);
          }
        }
    }
    return;
  }

  // ---- fused LayerNorm (N==128, full rows in block) ----
  #pragma unroll
  for (int i = 0; i < 2; ++i) {
    #pragma unroll
    for (int reg = 0; reg < 4; ++reg) {
      float s = 0.f, q = 0.f;
      #pragma unroll
      for (int j = 0; j < 4; ++j) {
        const float v = acc[i][j][reg];
        s += v; q += v * v;
      }
      #pragma unroll
      for (int off = 8; off >= 1; off >>= 1) {
        s += __shfl_xor(s, off, 16);
        q += __shfl_xor(q, off, 16);
      }
      if (l15 == 0) stats[wr * 32 + i * 16 + quad * 4 + reg][wc] = make_float2(s, q);
    }
  }
  __syncthreads();
  #pragma unroll
  for (int i = 0; i < 2; ++i) {
    #pragma unroll
    for (int reg = 0; reg < 4; ++reg) {
      const int mloc = wr * 32 + i * 16 + quad * 4 + reg;
      const float2 s0 = stats[mloc][0], s1 = stats[mloc][1];
      const float mean = (s0.x + s1.x) * (1.0f / 128.f);
      const float var  = (s0.y + s1.y) * (1.0f / 128.f) - mean * mean;
      const float r    = rsqrtf(var + 1e-5f);
      #pragma unroll
      for (int j = 0; j < 4; ++j) {
        const int n = wc * 64 + j * 16 + l15;
        pp.outB[(size_t)(m0 + mloc) * 128 + n] =
            bf((acc[i][j][reg] - mean) * r * pp.g[n] + pp.b[n]);
      }
    }
  }
}

// ---------------------------------------------------------------------------
// MFMA flash attention (shared softmax), bf16 I/O, no max subtraction,
// lane-local denominators. 128 q-rows / block (wave owns 32 rows).
// ---------------------------------------------------------------------------
__global__ __launch_bounds__(256) void attn_k(const u16* __restrict__ qx,
                                              const u16* __restrict__ kx,
                                              const u16* __restrict__ vx,
                                              const u16* __restrict__ qy,
                                              const u16* __restrict__ ky,
                                              const u16* __restrict__ vy,
                                              u16* __restrict__ o1,
                                              u16* __restrict__ o2) {
  const int t0 = blockIdx.x * 128;
  const int bh = blockIdx.y;
  const int b = bh >> 3, h = bh & 7;
  const size_t base = (size_t)b * TT * DDIM + h * DHH;

  __shared__ __align__(16) u16 Ks[64][40];   // [s][d0..31]
  __shared__ __align__(16) u16 Vt[32][72];   // [c][s0..63]
  __shared__ __align__(16) u16 Ps[128][72];  // [q][s0..63]

  const int tid  = threadIdx.x;
  const int w    = tid >> 6;
  const int lane = tid & 63;
  const int l15  = lane & 15;
  const int quad = lane >> 4;

  // Q A-fragments for the wave's 2 row-tiles
  const u16* qp = (quad < 2) ? qx : qy;
  const int dq = (quad & 1) * 8;
  short8 qa[2];
  #pragma unroll
  for (int u = 0; u < 2; ++u)
    qa[u] = *(const short8*)(qp + base + (size_t)(t0 + w * 32 + u * 16 + l15) * DDIM + dq);

  f32x4 Of[2][2];
  #pragma unroll
  for (int u = 0; u < 2; ++u) { Of[u][0] = {0,0,0,0}; Of[u][1] = {0,0,0,0}; }
  float l_i[2][4] = {};

  for (int kt = 0; kt < TT / 64; ++kt) {
    const int s0 = kt * 64;

    // stage K: one 16B chunk per thread
    {
      const int s = tid >> 2, c = tid & 3;
      const u16* kp = (c < 2) ? kx : ky;
      const int d8 = (c & 1) * 8;
      *(short8*)&Ks[s][(c < 2 ? 0 : 16) + d8] =
          *(const short8*)(kp + base + (size_t)(s0 + s) * DDIM + d8);
    }
    // stage V transposed: Vt[c][s]
    #pragma unroll
    for (int t = tid; t < 512; t += 256) {
      const int c = t & 31;
      const int sb = (t >> 5) << 2;
      const u16* vp = (c < 16) ? vx : vy;
      const int cc = c & 15;
      const size_t ro = base + (size_t)(s0 + sb) * DDIM + cc;
      ushort4 w4;
      w4.x = vp[ro];
      w4.y = vp[ro + DDIM];
      w4.z = vp[ro + 2 * DDIM];
      w4.w = vp[ro + 3 * DDIM];
      *(ushort4*)&Vt[c][sb] = w4;
    }
    __syncthreads();

    // S = Q'.K'^T + exp (both row-tiles)
    #pragma unroll
    for (int u = 0; u < 2; ++u) {
      f32x4 Sf[4];
      #pragma unroll
      for (int t = 0; t < 4; ++t) {
        short8 kb = *(const short8*)&Ks[t * 16 + l15][quad * 8];
        f32x4 z = {0.f, 0.f, 0.f, 0.f};
        Sf[t] = __builtin_amdgcn_mfma_f32_16x16x32_bf16(qa[u], kb, z, 0, 0, 0);
      }
      #pragma unroll
      for (int reg = 0; reg < 4; ++reg) {
        const float p0 = __expf(Sf[0][reg] * 0.125f);
        const float p1 = __expf(Sf[1][reg] * 0.125f);
        const float p2 = __expf(Sf[2][reg] * 0.125f);
        const float p3 = __expf(Sf[3][reg] * 0.125f);
        l_i[u][reg] += p0 + p1 + p2 + p3;
        const int q = w * 32 + u * 16 + quad * 4 + reg;
        Ps[q][l15]      = bf(p0);
        Ps[q][16 + l15] = bf(p1);
        Ps[q][32 + l15] = bf(p2);
        Ps[q][48 + l15] = bf(p3);
      }
    }

    // O += P @ V'  (same-wave LDS producer/consumer: no barrier needed)
    #pragma unroll
    for (int sh = 0; sh < 2; ++sh) {
      short8 vb0 = *(const short8*)&Vt[l15][sh * 32 + quad * 8];
      short8 vb1 = *(const short8*)&Vt[16 + l15][sh * 32 + quad * 8];
      #pragma unroll
      for (int u = 0; u < 2; ++u) {
        short8 pa = *(const short8*)&Ps[w * 32 + u * 16 + l15][sh * 32 + quad * 8];
        Of[u][0] = __builtin_amdgcn_mfma_f32_16x16x32_bf16(pa, vb0, Of[u][0], 0, 0, 0);
        Of[u][1] = __builtin_amdgcn_mfma_f32_16x16x32_bf16(pa, vb1, Of[u][1], 0, 0, 0);
      }
    }
    __syncthreads();
  }

  // epilogue: reduce denominators (16 lanes/row), normalize, write bf16
  #pragma unroll
  for (int u = 0; u < 2; ++u) {
    #pragma unroll
    for (int reg = 0; reg < 4; ++reg) {
      float l = l_i[u][reg];
      #pragma unroll
      for (int off = 8; off >= 1; off >>= 1) l += __shfl_xor(l, off, 16);
      const float inv = 1.0f / l;
      const size_t r = base + (size_t)(t0 + w * 32 + u * 16 + quad * 4 + reg) * DDIM + l15;
      o1[r] = bf(Of[u][0][reg] * inv);
      o2[r] = bf(Of[u][1][reg] * inv);
    }
  }
}

// ---------------------------------------------------------------------------
extern "C" void kernel_launch(void* const* d_in, const int* in_sizes, int n_in,
                              void* d_out, int out_size, void* d_ws, size_t ws_size,
                              hipStream_t stream) {
  const float* x_in  = (const float*)d_in[0];
  const float* y_in  = (const float*)d_in[1];
  const float* Wq    = (const float*)d_in[2];
  const float* Wk    = (const float*)d_in[3];
  const float* Wv    = (const float*)d_in[4];
  const float* Wox   = (const float*)d_in[5];
  const float* box   = (const float*)d_in[6];
  const float* Woy   = (const float*)d_in[7];
  const float* boy   = (const float*)d_in[8];
  const float* ln1xg = (const float*)d_in[9];
  const float* ln1xb = (const float*)d_in[10];
  const float* ln1yg = (const float*)d_in[11];
  const float* ln1yb = (const float*)d_in[12];
  const float* ln2xg = (const float*)d_in[13];
  const float* ln2xb = (const float*)d_in[14];
  const float* ln2yg = (const float*)d_in[15];
  const float* ln2yb = (const float*)d_in[16];
  const float* fxw1  = (const float*)d_in[17];
  const float* fxb1  = (const float*)d_in[18];
  const float* fxw2  = (const float*)d_in[19];
  const float* fxb2  = (const float*)d_in[20];
  const float* fyw1  = (const float*)d_in[21];
  const float* fyb1  = (const float*)d_in[22];
  const float* fyw2  = (const float*)d_in[23];
  const float* fyb2  = (const float*)d_in[24];

  const size_t S = (size_t)BT * DDIM;  // 1,048,576 elems
  float* X = (float*)d_out;
  float* Y = X + S;

  char* wsb = (char*)d_ws;
  auto carve = [&](size_t bytes) { char* p = wsb; wsb += (bytes + 255) & ~(size_t)255; return p; };
  u16* xn  = (u16*)carve(S * 2);
  u16* yn  = (u16*)carve(S * 2);
  u16* qx  = (u16*)carve(S * 2);
  u16* kx  = (u16*)carve(S * 2);
  u16* vx  = (u16*)carve(S * 2);
  u16* qy  = (u16*)carve(S * 2);
  u16* ky  = (u16*)carve(S * 2);
  u16* vy  = (u16*)carve(S * 2);
  u16* ob1 = (u16*)carve(S * 2);
  u16* ob2 = (u16*)carve(S * 2);
  u16* hx  = (u16*)carve(2 * S * 2);
  u16* hy  = (u16*)carve(2 * S * 2);
  u16* WqT[2], *WkT[2], *WvT[2], *WoxT[2], *WoyT[2];
  u16* f1xT[2], *f1yT[2], *f2xT[2], *f2yT[2];
  for (int l = 0; l < 2; ++l) {
    WqT[l]  = (u16*)carve(16384 * 2);
    WkT[l]  = (u16*)carve(16384 * 2);
    WvT[l]  = (u16*)carve(16384 * 2);
    WoxT[l] = (u16*)carve(16384 * 2);
    WoyT[l] = (u16*)carve(16384 * 2);
    f1xT[l] = (u16*)carve(32768 * 2);
    f1yT[l] = (u16*)carve(32768 * 2);
    f2xT[l] = (u16*)carve(32768 * 2);
    f2yT[l] = (u16*)carve(32768 * 2);
  }

  // weight transpose+convert (all layers, one kernel)
  {
    PrepArgs a;
    int idx = 0;
    for (int l = 0; l < 2; ++l) {
      a.p[idx++] = {Wq  + (size_t)l * 16384, WqT[l],  128, 128};
      a.p[idx++] = {Wk  + (size_t)l * 16384, WkT[l],  128, 128};
      a.p[idx++] = {Wv  + (size_t)l * 16384, WvT[l],  128, 128};
      a.p[idx++] = {Wox + (size_t)l * 16384, WoxT[l], 128, 128};
      a.p[idx++] = {Woy + (size_t)l * 16384, WoyT[l], 128, 128};
      a.p[idx++] = {fxw1 + (size_t)l * 32768, f1xT[l], 128, 256};
      a.p[idx++] = {fyw1 + (size_t)l * 32768, f1yT[l], 128, 256};
      a.p[idx++] = {fxw2 + (size_t)l * 32768, f2xT[l], 256, 128};
      a.p[idx++] = {fyw2 + (size_t)l * 32768, f2yT[l], 256, 128};
    }
    prep_k<<<dim3(4, 4, 18), 256, 0, stream>>>(a);
  }

  // layer-0 LN1 (only standalone LN)
  ln0_k<<<dim3(BT / 4, 2), 256, 0, stream>>>(x_in, y_in, ln1xg, ln1xb, ln1yg, ln1yb, xn, yn);

  for (int l = 0; l < 2; ++l) {
    const size_t bo  = (size_t)l * DDIM;
    const size_t fbo = (size_t)l * FF;

    // QKV (6-way batched): pure bf16 out
    {
      GemmArgs a = {}; a.K = DDIM; a.N = DDIM; a.gelu = 0; a.ln = 0;
      a.p[0] = {yn, WqT[l], nullptr, nullptr, nullptr, qx, nullptr, nullptr};
      a.p[1] = {xn, WkT[l], nullptr, nullptr, nullptr, kx, nullptr, nullptr};
      a.p[2] = {xn, WvT[l], nullptr, nullptr, nullptr, vx, nullptr, nullptr};
      a.p[3] = {xn, WqT[l], nullptr, nullptr, nullptr, qy, nullptr, nullptr};
      a.p[4] = {yn, WkT[l], nullptr, nullptr, nullptr, ky, nullptr, nullptr};
      a.p[5] = {yn, WvT[l], nullptr, nullptr, nullptr, vy, nullptr, nullptr};
      gemmf_k<<<dim3(1, BT / 64, 6), 256, 0, stream>>>(a);
    }
    // fused attention
    attn_k<<<dim3(TT / 128, BB * HH), 256, 0, stream>>>(qx, kx, vx, qy, ky, vy, ob1, ob2);
    // output proj + residual + LN2 -> X (fp32) and xn (bf16)
    {
      const float* resx = (l == 0) ? x_in : X;
      const float* resy = (l == 0) ? y_in : Y;
      GemmArgs a = {}; a.K = DDIM; a.N = DDIM; a.gelu = 0; a.ln = 1;
      a.p[0] = {ob1, WoxT[l], box + bo, resx, X, xn, ln2xg + bo, ln2xb + bo};
      a.p[1] = {ob2, WoyT[l], boy + bo, resy, Y, yn, ln2yg + bo, ln2yb + bo};
      gemmf_k<<<dim3(1, BT / 64, 2), 256, 0, stream>>>(a);
    }
    // FFN1 + gelu (bf16 out)
    {
      GemmArgs a = {}; a.K = DDIM; a.N = FF; a.gelu = 1; a.ln = 0;
      a.p[0] = {xn, f1xT[l], fxb1 + fbo, nullptr, nullptr, hx, nullptr, nullptr};
      a.p[1] = {yn, f1yT[l], fyb1 + fbo, nullptr, nullptr, hy, nullptr, nullptr};
      gemmf_k<<<dim3(2, BT / 64, 2), 256, 0, stream>>>(a);
    }
    // FFN2 + residual -> X; layer 0 also fuses next layer's LN1 -> xn
    {
      GemmArgs a = {}; a.K = FF; a.N = DDIM; a.gelu = 0; a.ln = (l == 0) ? 1 : 0;
      if (l == 0) {
        a.p[0] = {hx, f2xT[l], fxb2 + bo, X, X, xn, ln1xg + DDIM, ln1xb + DDIM};
        a.p[1] = {hy, f2yT[l], fyb2 + bo, Y, Y, yn, ln1yg + DDIM, ln1yb + DDIM};
      } else {
        a.p[0] = {hx, f2xT[l], fxb2 + bo, X, X, nullptr, nullptr, nullptr};
        a.p[1] = {hy, f2yT[l], fyb2 + bo, Y, Y, nullptr, nullptr, nullptr};
      }
      gemmf_k<<<dim3(1, BT / 64, 2), 256, 0, stream>>>(a);
    }
  }
}

// Round 5
// 271.695 us; speedup vs baseline: 2.4510x; 1.1338x over previous
//
#include <hip/hip_runtime.h>
#include <cstddef>

#define BB   8
#define TT   1024
#define DDIM 128
#define HH   8
#define DHH  16
#define FF   256
#define BT   (BB * TT)   // 8192

typedef unsigned short u16;
typedef __attribute__((ext_vector_type(8))) short short8;
typedef __attribute__((ext_vector_type(4))) float f32x4;

__device__ __forceinline__ u16 bf(float x) {
  unsigned u = __builtin_bit_cast(unsigned, x);
  u += 0x7fffu + ((u >> 16) & 1u);   // RTN-even
  return (u16)(u >> 16);
}
__device__ __forceinline__ u16 bft(float x) {           // truncate (P in [0,1])
  return (u16)(__builtin_bit_cast(unsigned, x) >> 16);
}

// fast gelu: x * sigmoid(1.59577x(1 + 0.044715x^2))
__device__ __forceinline__ float gelu_f(float x) {
  const float t = x * (0.79788456f + 0.03567740814f * x * x);
  return x / (1.0f + __expf(-2.0f * t));
}

// ---------------------------------------------------------------------------
// Weight prep: fp32 (K,N) -> bf16 (N,K)  (transpose + convert), 18 matrices.
// ---------------------------------------------------------------------------
struct PrepP { const float* W; u16* Wt; int K; int N; };
struct PrepArgs { PrepP p[18]; };

__global__ __launch_bounds__(256) void prep_k(PrepArgs a) {
  const PrepP pp = a.p[blockIdx.z];
  const int n0 = blockIdx.x * 64, k0 = blockIdx.y * 64;
  if (n0 >= pp.N || k0 >= pp.K) return;
  __shared__ float tile[64][65];
  const int tid = threadIdx.x;
  #pragma unroll
  for (int t = tid; t < 1024; t += 256) {
    const int kk = t >> 4, nn4 = (t & 15) << 2;
    float4 v = *(const float4*)(pp.W + (size_t)(k0 + kk) * pp.N + n0 + nn4);
    tile[nn4 + 0][kk] = v.x; tile[nn4 + 1][kk] = v.y;
    tile[nn4 + 2][kk] = v.z; tile[nn4 + 3][kk] = v.w;
  }
  __syncthreads();
  #pragma unroll
  for (int t = tid; t < 1024; t += 256) {
    const int nn = t >> 4, kk4 = (t & 15) << 2;
    ushort4 o;
    o.x = bf(tile[nn][kk4 + 0]); o.y = bf(tile[nn][kk4 + 1]);
    o.z = bf(tile[nn][kk4 + 2]); o.w = bf(tile[nn][kk4 + 3]);
    *(ushort4*)(pp.Wt + (size_t)(n0 + nn) * pp.K + k0 + kk4) = o;
  }
}

// ---------------------------------------------------------------------------
// Standalone LN (layer-0 LN1 only): fp32 in -> bf16 out. 4 rows / 256-thr block.
// ---------------------------------------------------------------------------
__global__ __launch_bounds__(256) void ln0_k(const float* __restrict__ X,
                                             const float* __restrict__ Y,
                                             const float* __restrict__ gx,
                                             const float* __restrict__ bx,
                                             const float* __restrict__ gy,
                                             const float* __restrict__ by,
                                             u16* __restrict__ ox,
                                             u16* __restrict__ oy) {
  const int which = blockIdx.y;
  const float* in = which ? Y : X;
  const float* g  = which ? gy : gx;
  const float* b  = which ? by : bx;
  u16* out        = which ? oy : ox;
  const int row  = blockIdx.x * 4 + (threadIdx.x >> 6);
  const int lane = threadIdx.x & 63;

  float2 v = *(const float2*)(in + (size_t)row * DDIM + lane * 2);
  float s  = v.x + v.y;
  float sq = v.x * v.x + v.y * v.y;
  #pragma unroll
  for (int off = 32; off >= 1; off >>= 1) {
    s  += __shfl_xor(s, off);
    sq += __shfl_xor(sq, off);
  }
  const float mean = s * (1.0f / DDIM);
  const float var  = sq * (1.0f / DDIM) - mean * mean;
  const float r    = rsqrtf(var + 1e-5f);
  float2 gg = *(const float2*)(g + lane * 2);
  float2 bb = *(const float2*)(b + lane * 2);
  ushort2 o;
  o.x = bf((v.x - mean) * r * gg.x + bb.x);
  o.y = bf((v.y - mean) * r * gg.y + bb.y);
  *(ushort2*)(out + (size_t)row * DDIM + lane * 2) = o;
}

// ---------------------------------------------------------------------------
// bf16 MFMA GEMM with fused epilogue; 32x128 tile, 256 threads = 4 waves
// (wr = row-half of 16, wc = col-half of 64). BK=64.
//   C = A(M,K)bf16 @ Wt(N,K)bf16 [+bias][gelu][+res fp32]
//   -> outF fp32 raw (residual stream) and/or outB bf16;
//   if ln: per-row LayerNorm fused (N==128, gridDim.x==1), normalized -> outB.
// ---------------------------------------------------------------------------
struct GemmP { const u16* A; const u16* Wt; const float* bias; const float* res;
               float* outF; u16* outB; const float* g; const float* b; };
struct GemmArgs { GemmP p[6]; int K; int N; int gelu; int ln; };

__global__ __launch_bounds__(256) void gemmf_k(GemmArgs a) {
  const GemmP pp = a.p[blockIdx.z];
  const int K = a.K, N = a.N;
  const int n0 = blockIdx.x * 128, m0 = blockIdx.y * 32;
  __shared__ __align__(16) u16 As[32][72];
  __shared__ __align__(16) u16 Bs[128][72];
  __shared__ float2 stats[32][2];
  const int tid  = threadIdx.x;
  const int w    = tid >> 6;
  const int lane = tid & 63;
  const int l15  = lane & 15;
  const int quad = lane >> 4;
  const int wr = w & 1, wc = w >> 1;

  f32x4 acc[4];
  #pragma unroll
  for (int j = 0; j < 4; ++j) acc[j] = {0.f, 0.f, 0.f, 0.f};

  for (int k0 = 0; k0 < K; k0 += 64) {
    {
      const int row = tid >> 3, c8 = (tid & 7) << 3;
      *(short8*)&As[row][c8] = *(const short8*)(pp.A + (size_t)(m0 + row) * K + k0 + c8);
    }
    #pragma unroll
    for (int t = tid; t < 1024; t += 256) {
      const int row = t >> 3, c8 = (t & 7) << 3;
      *(short8*)&Bs[row][c8] = *(const short8*)(pp.Wt + (size_t)(n0 + row) * K + k0 + c8);
    }
    __syncthreads();
    #pragma unroll
    for (int ks = 0; ks < 2; ++ks) {
      short8 ar = *(const short8*)&As[wr * 16 + l15][ks * 32 + quad * 8];
      #pragma unroll
      for (int j = 0; j < 4; ++j) {
        short8 br = *(const short8*)&Bs[wc * 64 + j * 16 + l15][ks * 32 + quad * 8];
        acc[j] = __builtin_amdgcn_mfma_f32_16x16x32_bf16(ar, br, acc[j], 0, 0, 0);
      }
    }
    __syncthreads();
  }

  // ---- epilogue: bias / gelu / res, raw fp32 store ----
  #pragma unroll
  for (int j = 0; j < 4; ++j) {
    const int n = n0 + wc * 64 + j * 16 + l15;
    const float bias_v = pp.bias ? pp.bias[n] : 0.f;
    #pragma unroll
    for (int reg = 0; reg < 4; ++reg) {
      const int m = m0 + wr * 16 + quad * 4 + reg;
      float v = acc[j][reg] + bias_v;
      if (a.gelu) v = gelu_f(v);
      if (pp.res) v += pp.res[(size_t)m * N + n];
      acc[j][reg] = v;
      if (pp.outF) pp.outF[(size_t)m * N + n] = v;
    }
  }

  if (!a.ln) {
    if (pp.outB) {
      #pragma unroll
      for (int j = 0; j < 4; ++j) {
        const int n = n0 + wc * 64 + j * 16 + l15;
        #pragma unroll
        for (int reg = 0; reg < 4; ++reg) {
          const int m = m0 + wr * 16 + quad * 4 + reg;
          pp.outB[(size_t)m * N + n] = bf(acc[j][reg]);
        }
      }
    }
    return;
  }

  // ---- fused LayerNorm (N==128: both col-halves in this block) ----
  #pragma unroll
  for (int reg = 0; reg < 4; ++reg) {
    float s = 0.f, q = 0.f;
    #pragma unroll
    for (int j = 0; j < 4; ++j) { const float v = acc[j][reg]; s += v; q += v * v; }
    #pragma unroll
    for (int off = 8; off >= 1; off >>= 1) {
      s += __shfl_xor(s, off, 16);
      q += __shfl_xor(q, off, 16);
    }
    if (l15 == 0) stats[wr * 16 + quad * 4 + reg][wc] = make_float2(s, q);
  }
  __syncthreads();
  #pragma unroll
  for (int reg = 0; reg < 4; ++reg) {
    const int mloc = wr * 16 + quad * 4 + reg;
    const float2 s0 = stats[mloc][0], s1 = stats[mloc][1];
    const float mean = (s0.x + s1.x) * (1.0f / 128.f);
    const float var  = (s0.y + s1.y) * (1.0f / 128.f) - mean * mean;
    const float r    = rsqrtf(var + 1e-5f);
    #pragma unroll
    for (int j = 0; j < 4; ++j) {
      const int n = wc * 64 + j * 16 + l15;
      pp.outB[(size_t)(m0 + mloc) * 128 + n] =
          bf((acc[j][reg] - mean) * r * pp.g[n] + pp.b[n]);
    }
  }
}

// ---------------------------------------------------------------------------
// MFMA flash attention (shared softmax). 64 q-rows / block (wave owns 16),
// double-buffered K/V staging: ONE barrier per key tile.
// ---------------------------------------------------------------------------
__global__ __launch_bounds__(256) void attn_k(const u16* __restrict__ qx,
                                              const u16* __restrict__ kx,
                                              const u16* __restrict__ vx,
                                              const u16* __restrict__ qy,
                                              const u16* __restrict__ ky,
                                              const u16* __restrict__ vy,
                                              u16* __restrict__ o1,
                                              u16* __restrict__ o2) {
  const int t0 = blockIdx.x * 64;
  const int bh = blockIdx.y;
  const int b = bh >> 3, h = bh & 7;
  const size_t base = (size_t)b * TT * DDIM + h * DHH;

  __shared__ __align__(16) u16 Ks[2][64][40];  // [buf][s][d0..31]
  __shared__ __align__(16) u16 Vt[2][32][72];  // [buf][c][s0..63]
  __shared__ __align__(16) u16 Ps[64][72];     // [q][s0..63] (wave-private rows)

  const int tid  = threadIdx.x;
  const int w    = tid >> 6;
  const int lane = tid & 63;
  const int l15  = lane & 15;
  const int quad = lane >> 4;

  // Q A-fragment: row m = l15, k = quad*8+j
  const u16* qp = (quad < 2) ? qx : qy;
  const int dq = (quad & 1) * 8;
  const short8 qa = *(const short8*)(qp + base + (size_t)(t0 + w * 16 + l15) * DDIM + dq);

  f32x4 Of0 = {0.f, 0.f, 0.f, 0.f};
  f32x4 Of1 = {0.f, 0.f, 0.f, 0.f};
  float l_i[4] = {0.f, 0.f, 0.f, 0.f};

  // staging params (uniform per thread)
  const int ks_s = tid >> 2, ks_c = tid & 3;
  const u16* ks_p = (ks_c < 2) ? kx : ky;
  const int ks_d8 = (ks_c & 1) * 8;
  const int ks_col = (ks_c < 2 ? 0 : 16) + ks_d8;

  #define STAGE(kt, buf)                                                          \
    do {                                                                          \
      const int s0_ = (kt) * 64;                                                  \
      *(short8*)&Ks[buf][ks_s][ks_col] =                                          \
          *(const short8*)(ks_p + base + (size_t)(s0_ + ks_s) * DDIM + ks_d8);    \
      _Pragma("unroll")                                                           \
      for (int t = tid; t < 512; t += 256) {                                      \
        const int c = t & 31;                                                     \
        const int sb = (t >> 5) << 2;                                             \
        const u16* vp = (c < 16) ? vx : vy;                                       \
        const int cc = c & 15;                                                    \
        const size_t ro = base + (size_t)(s0_ + sb) * DDIM + cc;                  \
        ushort4 w4;                                                               \
        w4.x = vp[ro];                                                            \
        w4.y = vp[ro + DDIM];                                                     \
        w4.z = vp[ro + 2 * DDIM];                                                 \
        w4.w = vp[ro + 3 * DDIM];                                                 \
        *(ushort4*)&Vt[buf][c][sb] = w4;                                          \
      }                                                                           \
    } while (0)

  STAGE(0, 0);

  for (int kt = 0; kt < TT / 64; ++kt) {
    const int buf = kt & 1;
    __syncthreads();
    if (kt + 1 < TT / 64) STAGE(kt + 1, buf ^ 1);

    // S = Q'.K'^T : 4 MFMAs
    f32x4 Sf[4];
    #pragma unroll
    for (int t = 0; t < 4; ++t) {
      short8 kb = *(const short8*)&Ks[buf][t * 16 + l15][quad * 8];
      f32x4 z = {0.f, 0.f, 0.f, 0.f};
      Sf[t] = __builtin_amdgcn_mfma_f32_16x16x32_bf16(qa, kb, z, 0, 0, 0);
    }

    // p = exp2(S * 0.125*log2e); lane-local denominators; truncate-pack to LDS
    #pragma unroll
    for (int reg = 0; reg < 4; ++reg) {
      const float p0 = exp2f(Sf[0][reg] * 0.18033688011112042f);
      const float p1 = exp2f(Sf[1][reg] * 0.18033688011112042f);
      const float p2 = exp2f(Sf[2][reg] * 0.18033688011112042f);
      const float p3 = exp2f(Sf[3][reg] * 0.18033688011112042f);
      l_i[reg] += p0 + p1 + p2 + p3;
      const int q = w * 16 + quad * 4 + reg;
      Ps[q][l15]      = bft(p0);
      Ps[q][16 + l15] = bft(p1);
      Ps[q][32 + l15] = bft(p2);
      Ps[q][48 + l15] = bft(p3);
    }

    // O += P @ V'   (wave-private Ps rows: no barrier needed)
    #pragma unroll
    for (int sh = 0; sh < 2; ++sh) {
      short8 pa  = *(const short8*)&Ps[w * 16 + l15][sh * 32 + quad * 8];
      short8 vb0 = *(const short8*)&Vt[buf][l15][sh * 32 + quad * 8];
      short8 vb1 = *(const short8*)&Vt[buf][16 + l15][sh * 32 + quad * 8];
      Of0 = __builtin_amdgcn_mfma_f32_16x16x32_bf16(pa, vb0, Of0, 0, 0, 0);
      Of1 = __builtin_amdgcn_mfma_f32_16x16x32_bf16(pa, vb1, Of1, 0, 0, 0);
    }
  }
  #undef STAGE

  // epilogue: reduce denominators (16 lanes/row), normalize, write bf16
  #pragma unroll
  for (int reg = 0; reg < 4; ++reg) {
    float l = l_i[reg];
    #pragma unroll
    for (int off = 8; off >= 1; off >>= 1) l += __shfl_xor(l, off, 16);
    const float inv = 1.0f / l;
    const size_t r = base + (size_t)(t0 + w * 16 + quad * 4 + reg) * DDIM + l15;
    o1[r] = bf(Of0[reg] * inv);
    o2[r] = bf(Of1[reg] * inv);
  }
}

// ---------------------------------------------------------------------------
extern "C" void kernel_launch(void* const* d_in, const int* in_sizes, int n_in,
                              void* d_out, int out_size, void* d_ws, size_t ws_size,
                              hipStream_t stream) {
  const float* x_in  = (const float*)d_in[0];
  const float* y_in  = (const float*)d_in[1];
  const float* Wq    = (const float*)d_in[2];
  const float* Wk    = (const float*)d_in[3];
  const float* Wv    = (const float*)d_in[4];
  const float* Wox   = (const float*)d_in[5];
  const float* box   = (const float*)d_in[6];
  const float* Woy   = (const float*)d_in[7];
  const float* boy   = (const float*)d_in[8];
  const float* ln1xg = (const float*)d_in[9];
  const float* ln1xb = (const float*)d_in[10];
  const float* ln1yg = (const float*)d_in[11];
  const float* ln1yb = (const float*)d_in[12];
  const float* ln2xg = (const float*)d_in[13];
  const float* ln2xb = (const float*)d_in[14];
  const float* ln2yg = (const float*)d_in[15];
  const float* ln2yb = (const float*)d_in[16];
  const float* fxw1  = (const float*)d_in[17];
  const float* fxb1  = (const float*)d_in[18];
  const float* fxw2  = (const float*)d_in[19];
  const float* fxb2  = (const float*)d_in[20];
  const float* fyw1  = (const float*)d_in[21];
  const float* fyb1  = (const float*)d_in[22];
  const float* fyw2  = (const float*)d_in[23];
  const float* fyb2  = (const float*)d_in[24];

  const size_t S = (size_t)BT * DDIM;  // 1,048,576 elems
  float* X = (float*)d_out;
  float* Y = X + S;

  char* wsb = (char*)d_ws;
  auto carve = [&](size_t bytes) { char* p = wsb; wsb += (bytes + 255) & ~(size_t)255; return p; };
  u16* xn  = (u16*)carve(S * 2);
  u16* yn  = (u16*)carve(S * 2);
  u16* qx  = (u16*)carve(S * 2);
  u16* kx  = (u16*)carve(S * 2);
  u16* vx  = (u16*)carve(S * 2);
  u16* qy  = (u16*)carve(S * 2);
  u16* ky  = (u16*)carve(S * 2);
  u16* vy  = (u16*)carve(S * 2);
  u16* ob1 = (u16*)carve(S * 2);
  u16* ob2 = (u16*)carve(S * 2);
  u16* hx  = (u16*)carve(2 * S * 2);
  u16* hy  = (u16*)carve(2 * S * 2);
  u16* WqT[2], *WkT[2], *WvT[2], *WoxT[2], *WoyT[2];
  u16* f1xT[2], *f1yT[2], *f2xT[2], *f2yT[2];
  for (int l = 0; l < 2; ++l) {
    WqT[l]  = (u16*)carve(16384 * 2);
    WkT[l]  = (u16*)carve(16384 * 2);
    WvT[l]  = (u16*)carve(16384 * 2);
    WoxT[l] = (u16*)carve(16384 * 2);
    WoyT[l] = (u16*)carve(16384 * 2);
    f1xT[l] = (u16*)carve(32768 * 2);
    f1yT[l] = (u16*)carve(32768 * 2);
    f2xT[l] = (u16*)carve(32768 * 2);
    f2yT[l] = (u16*)carve(32768 * 2);
  }

  // weight transpose+convert (all layers, one kernel)
  {
    PrepArgs a;
    int idx = 0;
    for (int l = 0; l < 2; ++l) {
      a.p[idx++] = {Wq  + (size_t)l * 16384, WqT[l],  128, 128};
      a.p[idx++] = {Wk  + (size_t)l * 16384, WkT[l],  128, 128};
      a.p[idx++] = {Wv  + (size_t)l * 16384, WvT[l],  128, 128};
      a.p[idx++] = {Wox + (size_t)l * 16384, WoxT[l], 128, 128};
      a.p[idx++] = {Woy + (size_t)l * 16384, WoyT[l], 128, 128};
      a.p[idx++] = {fxw1 + (size_t)l * 32768, f1xT[l], 128, 256};
      a.p[idx++] = {fyw1 + (size_t)l * 32768, f1yT[l], 128, 256};
      a.p[idx++] = {fxw2 + (size_t)l * 32768, f2xT[l], 256, 128};
      a.p[idx++] = {fyw2 + (size_t)l * 32768, f2yT[l], 256, 128};
    }
    prep_k<<<dim3(4, 4, 18), 256, 0, stream>>>(a);
  }

  // layer-0 LN1 (only standalone LN)
  ln0_k<<<dim3(BT / 4, 2), 256, 0, stream>>>(x_in, y_in, ln1xg, ln1xb, ln1yg, ln1yb, xn, yn);

  for (int l = 0; l < 2; ++l) {
    const size_t bo  = (size_t)l * DDIM;
    const size_t fbo = (size_t)l * FF;

    // QKV (6-way batched): pure bf16 out
    {
      GemmArgs a = {}; a.K = DDIM; a.N = DDIM; a.gelu = 0; a.ln = 0;
      a.p[0] = {yn, WqT[l], nullptr, nullptr, nullptr, qx, nullptr, nullptr};
      a.p[1] = {xn, WkT[l], nullptr, nullptr, nullptr, kx, nullptr, nullptr};
      a.p[2] = {xn, WvT[l], nullptr, nullptr, nullptr, vx, nullptr, nullptr};
      a.p[3] = {xn, WqT[l], nullptr, nullptr, nullptr, qy, nullptr, nullptr};
      a.p[4] = {yn, WkT[l], nullptr, nullptr, nullptr, ky, nullptr, nullptr};
      a.p[5] = {yn, WvT[l], nullptr, nullptr, nullptr, vy, nullptr, nullptr};
      gemmf_k<<<dim3(1, BT / 32, 6), 256, 0, stream>>>(a);
    }
    // fused attention
    attn_k<<<dim3(TT / 64, BB * HH), 256, 0, stream>>>(qx, kx, vx, qy, ky, vy, ob1, ob2);
    // output proj + residual + LN2 -> X (fp32) and xn (bf16)
    {
      const float* resx = (l == 0) ? x_in : X;
      const float* resy = (l == 0) ? y_in : Y;
      GemmArgs a = {}; a.K = DDIM; a.N = DDIM; a.gelu = 0; a.ln = 1;
      a.p[0] = {ob1, WoxT[l], box + bo, resx, X, xn, ln2xg + bo, ln2xb + bo};
      a.p[1] = {ob2, WoyT[l], boy + bo, resy, Y, yn, ln2yg + bo, ln2yb + bo};
      gemmf_k<<<dim3(1, BT / 32, 2), 256, 0, stream>>>(a);
    }
    // FFN1 + gelu (bf16 out)
    {
      GemmArgs a = {}; a.K = DDIM; a.N = FF; a.gelu = 1; a.ln = 0;
      a.p[0] = {xn, f1xT[l], fxb1 + fbo, nullptr, nullptr, hx, nullptr, nullptr};
      a.p[1] = {yn, f1yT[l], fyb1 + fbo, nullptr, nullptr, hy, nullptr, nullptr};
      gemmf_k<<<dim3(2, BT / 32, 2), 256, 0, stream>>>(a);
    }
    // FFN2 + residual -> X; layer 0 also fuses next layer's LN1 -> xn
    {
      GemmArgs a = {}; a.K = FF; a.N = DDIM; a.gelu = 0; a.ln = (l == 0) ? 1 : 0;
      if (l == 0) {
        a.p[0] = {hx, f2xT[l], fxb2 + bo, X, X, xn, ln1xg + DDIM, ln1xb + DDIM};
        a.p[1] = {hy, f2yT[l], fyb2 + bo, Y, Y, yn, ln1yg + DDIM, ln1yb + DDIM};
      } else {
        a.p[0] = {hx, f2xT[l], fxb2 + bo, X, X, nullptr, nullptr, nullptr};
        a.p[1] = {hy, f2yT[l], fyb2 + bo, Y, Y, nullptr, nullptr, nullptr};
      }
      gemmf_k<<<dim3(1, BT / 32, 2), 256, 0, stream>>>(a);
    }
  }
}